// Round 2
// baseline (588.654 us; speedup 1.0000x reference)
//
#include <hip/hip_runtime.h>
#include <math.h>

#define Bn 32
#define Tn 64
#define An 6
#define Ln 32
#define Hn 128
#define FDn 256
#define Nimg (Bn*Tn)   // 2048

typedef __attribute__((ext_vector_type(8))) short frag_ab;     // 8 bf16
typedef __attribute__((ext_vector_type(4))) float frag_cd;     // 4 fp32
typedef __attribute__((ext_vector_type(8))) _Float16 frag_h;   // 8 f16

__device__ __forceinline__ float sigmoid_fast(float x){
  return __builtin_amdgcn_rcpf(1.f + __expf(-x));
}
__device__ __forceinline__ float tanh_fast(float x){
  float x2 = fminf(fmaxf(2.f*x, -30.f), 30.f);
  float e = __expf(x2);
  return (e - 1.f) * __builtin_amdgcn_rcpf(e + 1.f);
}

__device__ __forceinline__ unsigned short f2bf(float f){
  unsigned int u = __float_as_uint(f);
  unsigned int r = (u + 0x7fffu + ((u >> 16) & 1u)) >> 16;
  return (unsigned short)r;
}
__device__ __forceinline__ unsigned short f2h(float f){
  union { _Float16 h; unsigned short u; } x; x.h = (_Float16)f; return x.u;
}
// barrier without vmcnt drain: global loads/stores in flight stay in flight
#define BAR_LDS() asm volatile("s_waitcnt lgkmcnt(0)\n\ts_barrier" ::: "memory")

// LDS fragment addressing with XOR row swizzle (units: unsigned short)
//  write: row r (within tile), k-piece p (8 elems) of a 16x32 fragment
__device__ __forceinline__ int swz_w(int r, int p){
  return ((r >> 4) << 9) + (p << 7) + ((((r & 15) ^ (p << 2))) << 3);
}
//  read: fragment f, lane l  (row = l&15, piece = l>>4)
__device__ __forceinline__ int swz_r(int f, int l){
  return (f << 9) + ((l >> 4) << 7) + ((((l & 15) ^ ((l >> 4) << 2))) << 3);
}

// ---------------------------------------------------------------------------
// states: (2048, 3, 64, 64) fp32 NCHW -> (2048, 64, 64, 4) bf16 NHWC (c3 = 0)
// ---------------------------------------------------------------------------
__global__ void __launch_bounds__(256)
states_nhwc_kernel(const float* __restrict__ src, unsigned short* __restrict__ dst)
{
  int idx = blockIdx.x*256 + threadIdx.x;      // 2048*4096
  int n = idx >> 12, pix = idx & 4095;
  const float* s = src + (size_t)n*3*4096 + pix;
  union { unsigned short e[4]; uint2 v; } u;
  u.e[0] = f2bf(s[0]); u.e[1] = f2bf(s[4096]); u.e[2] = f2bf(s[8192]); u.e[3] = 0;
  *(uint2*)(dst + (size_t)idx*4) = u.v;
}

// ---------------------------------------------------------------------------
// merged prep: conv/fc weight permute->bf16 (tap-major, c-fast) + MFMA-scan
// weight fragment packs (f16, per-lane-contiguous) + GIA/eps precompute.
//
// Scan fragment layouts (16x16x32 f16 MFMA, verified via conv kernel):
//   A-frag: lane l holds row (l&15), k = (l>>4)*8 + j  (j=0..7)
//   B-frag: lane l holds out-row (l&15), k = (l>>4)*8 + j
//   D:      m = (l>>4)*4 + reg, n = (l&15)
// Packs store [tile][lane][8] so a lane loads its frag with one dwordx4.
// ---------------------------------------------------------------------------
__global__ void __launch_bounds__(256)
prep2_kernel(const float* __restrict__ c1w, const float* __restrict__ c2w,
             const float* __restrict__ c3w, const float* __restrict__ c4w,
             const float* __restrict__ fcw,
             const float* __restrict__ gwhh, const float* __restrict__ gwih,
             const float* __restrict__ prw,  const float* __restrict__ pow_,
             const float* __restrict__ actions, const float* __restrict__ bih,
             const float* __restrict__ bhh,  const float* __restrict__ eps,
             unsigned short* __restrict__ w1p, unsigned short* __restrict__ w2p,
             unsigned short* __restrict__ w3p, unsigned short* __restrict__ w4p,
             unsigned short* __restrict__ wfcp,
             unsigned short* __restrict__ gWhh, unsigned short* __restrict__ gWz,
             unsigned short* __restrict__ gWpo, unsigned short* __restrict__ gWpr,
             float* __restrict__ GIA, float* __restrict__ gEps)
{
  const int bid = blockIdx.x, tid = threadIdx.x;
  if (bid < 128){            // c2: (64,32,16) -> [k][tap*32+c]
    int idx = bid*256+tid;
    int k = idx >> 9, r = idx & 511, tap = r >> 5, c = r & 31;
    w2p[idx] = f2bf(c2w[k*512 + c*16 + tap]);
  } else if (bid < 640){     // c3: (128,64,16)
    int idx = (bid-128)*256+tid;
    int k = idx >> 10, r = idx & 1023, tap = r >> 6, c = r & 63;
    w3p[idx] = f2bf(c3w[k*1024 + c*16 + tap]);
  } else if (bid < 2688){    // c4: (256,128,16)
    int idx = (bid-640)*256+tid;
    int k = idx >> 11, r = idx & 2047, tap = r >> 7, c = r & 127;
    w4p[idx] = f2bf(c4w[k*2048 + c*16 + tap]);
  } else if (bid < 6784){    // fc: [o][sp*256+c] = src[o*4096 + c*16 + sp]
    int idx = (bid-2688)*256+tid;
    int o = idx >> 12, r = idx & 4095, sp = r >> 8, c = r & 255;
    wfcp[idx] = f2bf(fcw[o*4096 + c*16 + sp]);
  } else if (bid < 6792){    // c1: (32,3,16) -> [k][tap*4+c], c3=0
    int idx = (bid-6784)*256+tid;
    int k = idx >> 6, r = idx & 63, tap = r >> 2, c = r & 3;
    w1p[idx] = (c < 3) ? f2bf(c1w[k*48 + c*16 + tap]) : (unsigned short)0;
  } else if (bid < 6984){    // gWhh: [nt(24)][kt(4)][lane(64)][8] f16
    int idx = (bid-6792)*256+tid;          // 0..49151
    int nt = idx >> 11, kt = (idx >> 9) & 3;
    int li = (idx >> 3) & 63, j = idx & 7;
    gWhh[idx] = f2h(gwhh[(nt*16 + (li&15))*128 + (kt<<5) + ((li>>4)<<3) + j]);
  } else if (bid < 7032){    // gWz: [nt(24)][lane][8] — Wih cols 0..31 (z)
    int idx = (bid-6984)*256+tid;          // 0..12287
    int nt = idx >> 9, li = (idx >> 3) & 63, j = idx & 7;
    gWz[idx] = f2h(gwih[(nt*16 + (li&15))*38 + ((li>>4)<<3) + j]);
  } else if (bid < 7128){    // gWpo: [nt(4)][kt(12)][lane][8]  (k 0..127=h, 128..383=f)
    int idx = (bid-7032)*256+tid;          // 0..24575
    int nt = idx / 6144, rem = idx % 6144, kt = rem >> 9;
    int li = (idx >> 3) & 63, j = idx & 7;
    gWpo[idx] = f2h(pow_[(nt*16 + (li&15))*384 + (kt<<5) + ((li>>4)<<3) + j]);
  } else if (bid < 7160){    // gWpr: [nt(4)][kt(4)][lane][8]
    int idx = (bid-7128)*256+tid;          // 0..8191
    int nt = idx >> 11, kt = (idx >> 9) & 3;
    int li = (idx >> 3) & 63, j = idx & 7;
    gWpr[idx] = f2h(prw[(nt*16 + (li&15))*128 + (kt<<5) + ((li>>4)<<3) + j]);
  } else if (bid < 10232){   // GIA[g][t][n][m] = bih + a_t·Wih_a + (n<256 ? bhh : 0)
    int idx = (bid-7160)*256+tid;          // 0..786431
    int m = idx & 15, q = idx >> 4;
    int n = q % 384, q2 = q / 384;
    int t = q2 & 63, g = q2 >> 6;
    int b = g*16 + m;
    float v = bih[n] + (n < 256 ? bhh[n] : 0.f);
    const float* ar = actions + ((size_t)b*64 + t)*6;
    const float* wr = gwih + n*38 + 32;
#pragma unroll
    for (int k = 0; k < 6; k++) v += ar[k] * wr[k];
    GIA[idx] = v;
  } else {                   // gEps[g][t][o][m] = eps[b][t][o]
    int idx = (bid-10232)*256+tid;         // 0..65535
    int m = idx & 15, o = (idx >> 4) & 31, t = (idx >> 9) & 63, g = idx >> 15;
    gEps[idx] = eps[((size_t)(g*16 + m)*64 + t)*32 + o];
  }
}

// feats (2048,256) f32 -> A-frag pack gF[g][t][kt(8)][lane][8] f16
__global__ void __launch_bounds__(256)
feats_pack(const float* __restrict__ feats, unsigned short* __restrict__ gF)
{
  int idx = blockIdx.x*256 + threadIdx.x;   // 0..524287
  int j = idx & 7, li = (idx >> 3) & 63, kt = (idx >> 9) & 7;
  int t = (idx >> 12) & 63, g = idx >> 18;
  int r = li & 15, k = ((li >> 4) << 3) + j;
  gF[idx] = f2h(feats[(size_t)((g*16 + r)*64 + t)*256 + (kt<<5) + k]);
}

// ---------------------------------------------------------------------------
// NHWC implicit-GEMM conv (k=4, s=2, p=1), MFMA 16x16x32 bf16.  (unchanged)
// ---------------------------------------------------------------------------
template<int Cin, int IN, int Kout, int OUT, int BN, int LOG_SPB>
__global__ void __launch_bounds__(256)
convN_mfma(const unsigned short* __restrict__ in,
           const unsigned short* __restrict__ wB,
           const float* __restrict__ bias,
           unsigned short* __restrict__ out)
{
  constexpr int SPB = OUT*OUT;
  constexpr int KD  = 16*Cin;
  constexpr int NCH = KD/32;
  constexpr int NFN = BN/32;
  constexpr int BFR = BN/16;
  constexpr int BSL = (BN*4 + 255)/256;
  __shared__ __align__(16) unsigned short Alds[2][8*512];
  __shared__ __align__(16) unsigned short Blds[2][BFR*512];

  const int tid = threadIdx.x;
  const int wave = tid >> 6, lane = tid & 63;
  const unsigned m0 = blockIdx.x * 128;
  const int n0 = blockIdx.y * BN;

  const int p = tid & 3;
  const unsigned short* baseA[2]; int oyA[2], oxA[2]; int AdstI[2];
#pragma unroll
  for (int h = 0; h < 2; h++){
    int r = (tid >> 2) + h*64;
    unsigned m = m0 + r;
    int nimg = m >> LOG_SPB;
    int sp = m & (SPB - 1);
    oyA[h] = sp / OUT; oxA[h] = sp & (OUT - 1);
    baseA[h] = in + (size_t)nimg * IN * IN * Cin;
    AdstI[h] = swz_w(r, p);
  }

  const unsigned short* BsrcH[BSL]; int BdstIH[BSL]; bool bActH[BSL];
#pragma unroll
  for (int h = 0; h < BSL; h++){
    int bn = (tid >> 2) + h*64, pb = tid & 3;
    bActH[h] = bn < BN;
    BsrcH[h] = wB + (size_t)(n0 + bn)*KD + pb*8;
    BdstIH[h] = swz_w(bn, pb);
  }

  const int mhalf = wave >> 1, nhalf = wave & 1;
  frag_cd acc[4][NFN];
#pragma unroll
  for (int i = 0; i < 4; i++)
#pragma unroll
    for (int j = 0; j < NFN; j++) acc[i][j] = (frag_cd){0.f,0.f,0.f,0.f};

  auto loadA = [&](int kt, int h) -> uint4 {
    if constexpr (Cin >= 32){
      constexpr int CPT = Cin/32;
      int tap = kt / CPT;
      int c0 = (kt - tap*CPT)*32;
      int kh = tap >> 2, kw = tap & 3;
      int iy = 2*oyA[h] - 1 + kh;
      int ix = 2*oxA[h] - 1 + kw;
      uint4 v = {0u,0u,0u,0u};
      if ((unsigned)iy < (unsigned)IN && (unsigned)ix < (unsigned)IN)
        v = *(const uint4*)(baseA[h] + ((iy*IN + ix)*Cin + c0 + p*8));
      return v;
    } else {
      int kh = kt*2 + (p >> 1);
      int kw0 = (p & 1)*2;
      int iy = 2*oyA[h] - 1 + kh;
      int ix0 = 2*oxA[h] - 1 + kw0;
      union { uint2 u2[2]; uint4 u4; } v; v.u4 = (uint4){0u,0u,0u,0u};
      bool iyok = (unsigned)iy < (unsigned)IN;
      const unsigned short* rowp = baseA[h] + iy*IN*4;
#pragma unroll
      for (int d = 0; d < 2; d++){
        int ix = ix0 + d;
        if (iyok && (unsigned)ix < (unsigned)IN) v.u2[d] = *(const uint2*)(rowp + ix*4);
      }
      return v.u4;
    }
  };

  const int rdoff = swz_r(0, lane);

  uint4 aR0 = loadA(0,0), aR1 = loadA(0,1);
  uint4 bR[BSL];
#pragma unroll
  for (int h = 0; h < BSL; h++)
    bR[h] = bActH[h] ? *(const uint4*)BsrcH[h] : (uint4){0u,0u,0u,0u};
  *(uint4*)&Alds[0][AdstI[0]] = aR0;
  *(uint4*)&Alds[0][AdstI[1]] = aR1;
#pragma unroll
  for (int h = 0; h < BSL; h++)
    if (bActH[h]) *(uint4*)&Blds[0][BdstIH[h]] = bR[h];
  if (NCH > 1){
    aR0 = loadA(1,0); aR1 = loadA(1,1);
#pragma unroll
    for (int h = 0; h < BSL; h++)
      if (bActH[h]) bR[h] = *(const uint4*)(BsrcH[h] + 32);
  }
  BAR_LDS();

#pragma unroll 2
  for (int kt = 0; kt < NCH; kt++){
    const int cur = kt & 1, nxt = cur ^ 1;
    if (kt + 1 < NCH){
      *(uint4*)&Alds[nxt][AdstI[0]] = aR0;
      *(uint4*)&Alds[nxt][AdstI[1]] = aR1;
#pragma unroll
      for (int h = 0; h < BSL; h++)
        if (bActH[h]) *(uint4*)&Blds[nxt][BdstIH[h]] = bR[h];
      if (kt + 2 < NCH){
        aR0 = loadA(kt+2, 0);
        aR1 = loadA(kt+2, 1);
#pragma unroll
        for (int h = 0; h < BSL; h++)
          if (bActH[h]) bR[h] = *(const uint4*)(BsrcH[h] + (kt+2)*32);
      }
    }
    frag_ab a[4], bf[NFN];
#pragma unroll
    for (int i = 0; i < 4; i++)
      a[i] = *(const frag_ab*)&Alds[cur][(((mhalf<<2) + i) << 9) + rdoff];
#pragma unroll
    for (int j = 0; j < NFN; j++)
      bf[j] = *(const frag_ab*)&Blds[cur][((nhalf*NFN + j) << 9) + rdoff];
#pragma unroll
    for (int i = 0; i < 4; i++)
#pragma unroll
      for (int j = 0; j < NFN; j++)
        acc[i][j] = __builtin_amdgcn_mfma_f32_16x16x32_bf16(a[i], bf[j], acc[i][j], 0, 0, 0);
    BAR_LDS();
  }

  const unsigned mb = m0 + mhalf*64 + ((lane >> 4) << 2);
#pragma unroll
  for (int j = 0; j < NFN; j++){
    const int kg = n0 + nhalf*(NFN*16) + j*16 + (lane & 15);
    const float bv = bias[kg];
#pragma unroll
    for (int i = 0; i < 4; i++){
#pragma unroll
      for (int r = 0; r < 4; r++){
        unsigned mg = mb + i*16 + r;
        out[(size_t)mg*Kout + kg] = f2bf(fmaxf(acc[i][j][r] + bv, 0.f));
      }
    }
  }
}

// ---------------------------------------------------------------------------
// FC GEMM: A (2048 x 4096) bf16, W (256 x 4096) permuted.  (unchanged)
// ---------------------------------------------------------------------------
__global__ void __launch_bounds__(256)
fc_mfma2(const unsigned short* __restrict__ A, const unsigned short* __restrict__ wB,
         const float* __restrict__ bias, float* __restrict__ outF)
{
  constexpr int KD = 4096, NCH = KD/32;
  __shared__ __align__(16) unsigned short Alds[2][4*512];
  __shared__ __align__(16) unsigned short Blds[2][4*512];

  const int tid = threadIdx.x, wave = tid >> 6, lane = tid & 63;
  const int m0 = blockIdx.x * 64, n0 = blockIdx.y * 64;
  const int r = tid >> 2, pc = tid & 3;
  const unsigned short* Asrc = A + (size_t)(m0 + r)*KD + pc*8;
  const unsigned short* Bsrc = wB + (size_t)(n0 + r)*KD + pc*8;
  const int wI = swz_w(r, pc);
  const int mh = wave >> 1, nh = wave & 1;
  const int rdoff = swz_r(0, lane);

  frag_cd acc[2][2];
#pragma unroll
  for (int i = 0; i < 2; i++)
#pragma unroll
    for (int j = 0; j < 2; j++) acc[i][j] = (frag_cd){0.f,0.f,0.f,0.f};

  uint4 aP = *(const uint4*)Asrc, bP = *(const uint4*)Bsrc;
  *(uint4*)&Alds[0][wI] = aP;
  *(uint4*)&Blds[0][wI] = bP;
  aP = *(const uint4*)(Asrc + 32);
  bP = *(const uint4*)(Bsrc + 32);
  BAR_LDS();

#pragma unroll 2
  for (int kt = 0; kt < NCH; kt++){
    const int cur = kt & 1, nxt = cur ^ 1;
    if (kt + 1 < NCH){
      *(uint4*)&Alds[nxt][wI] = aP;
      *(uint4*)&Blds[nxt][wI] = bP;
      if (kt + 2 < NCH){
        aP = *(const uint4*)(Asrc + (kt+2)*32);
        bP = *(const uint4*)(Bsrc + (kt+2)*32);
      }
    }
    frag_ab a[2], b[2];
#pragma unroll
    for (int i = 0; i < 2; i++) a[i] = *(const frag_ab*)&Alds[cur][(((mh<<1)+i) << 9) + rdoff];
#pragma unroll
    for (int j = 0; j < 2; j++) b[j] = *(const frag_ab*)&Blds[cur][(((nh<<1)+j) << 9) + rdoff];
#pragma unroll
    for (int i = 0; i < 2; i++)
#pragma unroll
      for (int j = 0; j < 2; j++)
        acc[i][j] = __builtin_amdgcn_mfma_f32_16x16x32_bf16(a[i], b[j], acc[i][j], 0, 0, 0);
    BAR_LDS();
  }

  const int mb = m0 + mh*32 + ((lane >> 4) << 2);
#pragma unroll
  for (int j = 0; j < 2; j++){
    const int kg = n0 + nh*32 + j*16 + (lane & 15);
    const float bv = bias[kg];
#pragma unroll
    for (int i = 0; i < 2; i++)
#pragma unroll
      for (int rr = 0; rr < 4; rr++)
        outF[(size_t)(mb + i*16 + rr)*256 + kg] = acc[i][j][rr] + bv;
  }
}

// ---------------------------------------------------------------------------
// RSSM scan v5: MFMA-based. 2 blocks x 16 batch elems, 512 threads (8 waves).
// Waves 0..5 ("G"): gi/gh GEMM (4 n-tiles each, n = wv*64..+63); waves 4..5
// keep gi/gh separate (n-gate needs r*gh). Waves 6..7 ("P"): post GEMM —
// f-part in phase A (overlaps G), h-part in phase C; z sampled in-register.
// Prior (waves 0..1) in phase C. Weights live in registers as B-fragments;
// GIA (bias + action-dot) f32 prefetched one step ahead. f16 MFMA keeps
// numerics identical to the previous fdot2-f16 scan. 3 lgkm-only barriers/step.
// ---------------------------------------------------------------------------
__global__ void __launch_bounds__(512, 2)
rssm_mfma(const unsigned short* __restrict__ gWhh,
          const unsigned short* __restrict__ gWz,
          const unsigned short* __restrict__ gWpo,
          const unsigned short* __restrict__ gWpr,
          const unsigned short* __restrict__ gF,
          const float* __restrict__ GIA,
          const float* __restrict__ gEps,
          const float* __restrict__ bhh,
          const float* __restrict__ pr_b,
          const float* __restrict__ po_b,
          float* __restrict__ out)
{
  __shared__ __align__(16) unsigned short Hlds[4*512];   // h A-frags (f16)
  __shared__ __align__(16) unsigned short Zlds[512];     // z A-frag
  __shared__ __align__(16) float Ssum[16*256];           // gi+gh for r/z cols
  __shared__ __align__(16) float Gin[16*128];            // gi for n-gate cols
  __shared__ __align__(16) float Ghn[16*128];            // gh for n-gate cols

  const int g = blockIdx.x, tid = threadIdx.x;
  const int wv = tid >> 6, lane = tid & 63;
  const int dn = lane & 15, dm4 = (lane >> 4) << 2;
  const int l8 = lane << 3;
  const int rdoff = swz_r(0, lane);

  // gate-thread mapping: (batch gm, 4 consecutive j starting at gj)
  const int gm = tid & 15;
  const int gj = (tid >> 4) << 2;
  const int gxm = (gm & 7) << 2;
  const int hws = ((gj >> 5) << 9) + swz_w(gm, (gj & 31) >> 3) + (gj & 7);

  const int OFF_MUP = 0;
  const int OFF_LVP = Bn*Tn*Ln;
  const int OFF_MUQ = 2*Bn*Tn*Ln;
  const int OFF_LVQ = 3*Bn*Tn*Ln;
  const int OFF_H   = 4*Bn*Tn*Ln;
  const int OFF_Z   = 4*Bn*Tn*Ln + Bn*Tn*Hn;

  // zero h0 / z0
  ((uint2*)Hlds)[tid] = (uint2){0u,0u};
  if (tid < 128) ((uint2*)Zlds)[tid] = (uint2){0u,0u};

  float h_old[4] = {0.f,0.f,0.f,0.f};

  auto do_gates = [&](int t) {
    const int xr = gj ^ gxm;
    frag_cd vr = *(const frag_cd*)&Ssum[(gm<<8) + xr];
    frag_cd vz = *(const frag_cd*)&Ssum[(gm<<8) + 128 + xr];
    frag_cd vi = *(const frag_cd*)&Gin[(gm<<7) + xr];
    frag_cd vh = *(const frag_cd*)&Ghn[(gm<<7) + xr];
    float hnew[4];
#pragma unroll
    for (int q = 0; q < 4; q++){
      float rr = sigmoid_fast(vr[q]);
      float zz = sigmoid_fast(vz[q]);
      float nn = tanh_fast(fmaf(rr, vh[q], vi[q]));
      hnew[q] = (1.f - zz)*nn + zz*h_old[q];
      h_old[q] = hnew[q];
    }
    union { _Float16 h[4]; uint2 u; } hw;
#pragma unroll
    for (int q = 0; q < 4; q++) hw.h[q] = (_Float16)hnew[q];
    *(uint2*)&Hlds[hws] = hw.u;
    *(float4*)(out + OFF_H + (size_t)((g*16 + gm)*64 + t)*128 + gj) =
        (float4){hnew[0],hnew[1],hnew[2],hnew[3]};
  };

  if (wv < 6){
    // ---------------- G path ----------------
    frag_h Bhh[4][4], Bz[4];
    const int nt0 = wv << 2;
#pragma unroll
    for (int nt = 0; nt < 4; nt++){
#pragma unroll
      for (int kt = 0; kt < 4; kt++)
        Bhh[nt][kt] = *(const frag_h*)(gWhh + ((((nt0+nt)<<2) + kt)<<9) + l8);
      Bz[nt] = *(const frag_h*)(gWz + ((nt0+nt)<<9) + l8);
    }
    frag_h Bpr[2][4]; float prb2[2] = {0.f,0.f};
    if (wv < 2){
#pragma unroll
      for (int i = 0; i < 2; i++){
        int nt = (wv<<1) + i;
#pragma unroll
        for (int kt = 0; kt < 4; kt++)
          Bpr[i][kt] = *(const frag_h*)(gWpr + (((nt<<2)+kt)<<9) + l8);
        prb2[i] = pr_b[(nt<<4) + dn];
      }
    }
    float bhh4[4] = {0.f,0.f,0.f,0.f};
    if (wv >= 4){
#pragma unroll
      for (int nt = 0; nt < 4; nt++)
        bhh4[nt] = bhh[256 + ((wv-4)<<6) + (nt<<4) + dn];
    }
    frag_cd giaP[4];
#pragma unroll
    for (int nt = 0; nt < 4; nt++)
      giaP[nt] = *(const frag_cd*)(GIA + ((size_t)(g*64)*384 + (wv<<6) + (nt<<4) + dn)*16 + dm4);
    BAR_LDS();

    for (int t = 0; t < Tn; t++){
      // phase A: gi(z-part) + gh
      frag_h hA[4], zA;
      zA = *(const frag_h*)&Zlds[rdoff];
#pragma unroll
      for (int kt = 0; kt < 4; kt++)
        hA[kt] = *(const frag_h*)&Hlds[(kt<<9) + rdoff];
      if (wv < 4){
        frag_cd acc[4];
#pragma unroll
        for (int nt = 0; nt < 4; nt++){
          acc[nt] = giaP[nt];
          acc[nt] = __builtin_amdgcn_mfma_f32_16x16x32_f16(zA, Bz[nt], acc[nt], 0,0,0);
        }
#pragma unroll
        for (int kt = 0; kt < 4; kt++)
#pragma unroll
          for (int nt = 0; nt < 4; nt++)
            acc[nt] = __builtin_amdgcn_mfma_f32_16x16x32_f16(hA[kt], Bhh[nt][kt], acc[nt], 0,0,0);
#pragma unroll
        for (int nt = 0; nt < 4; nt++){
          const int n = (wv<<6) + (nt<<4) + dn;
#pragma unroll
          for (int r = 0; r < 4; r++){
            const int m = dm4 + r;
            Ssum[(m<<8) + (n ^ ((m&7)<<2))] = acc[nt][r];
          }
        }
      } else {
        frag_cd ai[4], ah[4];
#pragma unroll
        for (int nt = 0; nt < 4; nt++){
          ai[nt] = giaP[nt];
          ai[nt] = __builtin_amdgcn_mfma_f32_16x16x32_f16(zA, Bz[nt], ai[nt], 0,0,0);
          ah[nt] = (frag_cd){bhh4[nt],bhh4[nt],bhh4[nt],bhh4[nt]};
        }
#pragma unroll
        for (int kt = 0; kt < 4; kt++)
#pragma unroll
          for (int nt = 0; nt < 4; nt++)
            ah[nt] = __builtin_amdgcn_mfma_f32_16x16x32_f16(hA[kt], Bhh[nt][kt], ah[nt], 0,0,0);
#pragma unroll
        for (int nt = 0; nt < 4; nt++){
          const int jj = ((wv-4)<<6) + (nt<<4) + dn;
#pragma unroll
          for (int r = 0; r < 4; r++){
            const int m = dm4 + r;
            const int x = jj ^ ((m&7)<<2);
            Gin[(m<<7) + x] = ai[nt][r];
            Ghn[(m<<7) + x] = ah[nt][r];
          }
        }
      }
      BAR_LDS();   // BAR1: sums visible; H/Z reads done

      if (t < Tn-1){
#pragma unroll
        for (int nt = 0; nt < 4; nt++)
          giaP[nt] = *(const frag_cd*)(GIA + ((size_t)(g*64 + t+1)*384 + (wv<<6) + (nt<<4) + dn)*16 + dm4);
      }
      do_gates(t);
      BAR_LDS();   // BAR2: h_t visible

      if (wv < 2){
        frag_h hB[4];
#pragma unroll
        for (int kt = 0; kt < 4; kt++)
          hB[kt] = *(const frag_h*)&Hlds[(kt<<9) + rdoff];
        frag_cd ap[2];
#pragma unroll
        for (int i = 0; i < 2; i++) ap[i] = (frag_cd){prb2[i],prb2[i],prb2[i],prb2[i]};
#pragma unroll
        for (int kt = 0; kt < 4; kt++)
#pragma unroll
          for (int i = 0; i < 2; i++)
            ap[i] = __builtin_amdgcn_mfma_f32_16x16x32_f16(hB[kt], Bpr[i][kt], ap[i], 0,0,0);
#pragma unroll
        for (int i = 0; i < 2; i++){
          const int o = ((wv<<1)+i)*16 + dn;
#pragma unroll
          for (int r = 0; r < 4; r++){
            const size_t bt = (size_t)(g*16 + dm4 + r)*64 + t;
            if (wv == 0) out[OFF_MUP + bt*32 + o] = ap[i][r];
            else         out[OFF_LVP + bt*32 + (o-32)] = ap[i][r];
          }
        }
      }
      BAR_LDS();   // BAR3: z_t visible, buffers reusable
    }
  } else {
    // ---------------- P path (post) ----------------
    const int ow = wv - 6;                  // 0 or 1
    frag_h Bpo[2][12];
#pragma unroll
    for (int i = 0; i < 2; i++){
      const int nt = ow + (i<<1);           // wave6: o-tiles 0,2; wave7: 1,3
#pragma unroll
      for (int kt = 0; kt < 12; kt++)
        Bpo[i][kt] = *(const frag_h*)(gWpo + ((nt*12 + kt)<<9) + l8);
    }
    float pob2[2];
#pragma unroll
    for (int i = 0; i < 2; i++) pob2[i] = po_b[(ow + (i<<1))*16 + dn];
    const int oo = (ow<<4) + dn;            // mu output index (0..31)
    frag_h Ff[8];
#pragma unroll
    for (int kt = 0; kt < 8; kt++)
      Ff[kt] = *(const frag_h*)(gF + ((size_t)((g*64)*8 + kt)<<9) + l8);
    float4 epsP = *(const float4*)(gEps + ((size_t)(g*64)*32 + oo)*16 + dm4);
    BAR_LDS();

    for (int t = 0; t < Tn; t++){
      // phase A: f-part of post (overlaps G-waves' GEMM)
      frag_cd pacc[2];
#pragma unroll
      for (int i = 0; i < 2; i++) pacc[i] = (frag_cd){pob2[i],pob2[i],pob2[i],pob2[i]};
#pragma unroll
      for (int kt = 0; kt < 8; kt++)
#pragma unroll
        for (int i = 0; i < 2; i++)
          pacc[i] = __builtin_amdgcn_mfma_f32_16x16x32_f16(Ff[kt], Bpo[i][4+kt], pacc[i], 0,0,0);
      BAR_LDS();   // BAR1

      if (t < Tn-1){
#pragma unroll
        for (int kt = 0; kt < 8; kt++)
          Ff[kt] = *(const frag_h*)(gF + ((size_t)((g*64 + t+1)*8 + kt)<<9) + l8);
      }
      do_gates(t);
      BAR_LDS();   // BAR2

      // phase C: h-part of post + z sample
      frag_h hB[4];
#pragma unroll
      for (int kt = 0; kt < 4; kt++)
        hB[kt] = *(const frag_h*)&Hlds[(kt<<9) + rdoff];
#pragma unroll
      for (int kt = 0; kt < 4; kt++)
#pragma unroll
        for (int i = 0; i < 2; i++)
          pacc[i] = __builtin_amdgcn_mfma_f32_16x16x32_f16(hB[kt], Bpo[i][kt], pacc[i], 0,0,0);
#pragma unroll
      for (int r = 0; r < 4; r++){
        const size_t bt = (size_t)(g*16 + dm4 + r)*64 + t;
        const float mu = pacc[0][r], lv = pacc[1][r];
        out[OFF_MUQ + bt*32 + oo] = mu;
        out[OFF_LVQ + bt*32 + oo] = lv;
        const float zz = fmaf(__expf(0.5f*lv), (&epsP.x)[r], mu);
        out[OFF_Z + bt*32 + oo] = zz;
        Zlds[swz_w(dm4 + r, oo>>3) + (oo&7)] = f2h(zz);
      }
      if (t < Tn-1)
        epsP = *(const float4*)(gEps + ((size_t)(g*64 + t+1)*32 + oo)*16 + dm4);
      BAR_LDS();   // BAR3
    }
  }
}

// ---------------------------------------------------------------------------
extern "C" void kernel_launch(void* const* d_in, const int* in_sizes, int n_in,
                              void* d_out, int out_size, void* d_ws, size_t ws_size,
                              hipStream_t stream)
{
  const float* states = (const float*)d_in[0];
  const float* actions= (const float*)d_in[1];
  const float* c1_w = (const float*)d_in[2];  const float* c1_b = (const float*)d_in[3];
  const float* c2_w = (const float*)d_in[4];  const float* c2_b = (const float*)d_in[5];
  const float* c3_w = (const float*)d_in[6];  const float* c3_b = (const float*)d_in[7];
  const float* c4_w = (const float*)d_in[8];  const float* c4_b = (const float*)d_in[9];
  const float* fc_w = (const float*)d_in[10]; const float* fc_b = (const float*)d_in[11];
  const float* gwih = (const float*)d_in[12]; const float* gwhh = (const float*)d_in[13];
  const float* gbih = (const float*)d_in[14]; const float* gbhh = (const float*)d_in[15];
  const float* pr_w = (const float*)d_in[16]; const float* pr_b = (const float*)d_in[17];
  const float* po_w = (const float*)d_in[18]; const float* po_b = (const float*)d_in[19];
  const float* eps  = (const float*)d_in[20];

  char* p = (char*)d_ws;
  auto alloc = [&](size_t bytes){ char* r = p; p += (bytes + 255) & ~255ULL; return r; };

  unsigned short* statesB = (unsigned short*)alloc((size_t)Nimg*4096*4*2); // NHWC c=4
  unsigned short* act1    = (unsigned short*)alloc((size_t)Nimg*1024*32*2);
  unsigned short* act2    = (unsigned short*)alloc((size_t)Nimg*256*64*2);
  unsigned short* act3    = (unsigned short*)alloc((size_t)Nimg*64*128*2);
  unsigned short* act4    = (unsigned short*)alloc((size_t)Nimg*16*256*2);
  float*          feats   = (float*)alloc((size_t)Nimg*FDn*4);
  unsigned short* w1p     = (unsigned short*)alloc(32*64*2);
  unsigned short* w2p     = (unsigned short*)alloc((size_t)64*512*2);
  unsigned short* w3p     = (unsigned short*)alloc((size_t)128*1024*2);
  unsigned short* w4p     = (unsigned short*)alloc((size_t)256*2048*2);
  unsigned short* wfcp    = (unsigned short*)alloc((size_t)256*4096*2);
  unsigned short* gWhhp   = (unsigned short*)alloc((size_t)49152*2);
  unsigned short* gWzp    = (unsigned short*)alloc((size_t)12288*2);
  unsigned short* gWpop   = (unsigned short*)alloc((size_t)24576*2);
  unsigned short* gWprp   = (unsigned short*)alloc((size_t)8192*2);
  unsigned short* gFA     = (unsigned short*)alloc((size_t)524288*2);
  float*          GIAb    = (float*)alloc((size_t)786432*4);
  float*          gEpsb   = (float*)alloc((size_t)65536*4);

  states_nhwc_kernel<<<Nimg*4096/256, 256, 0, stream>>>(states, statesB);
  prep2_kernel<<<10488, 256, 0, stream>>>(c1_w, c2_w, c3_w, c4_w, fc_w,
                                          gwhh, gwih, pr_w, po_w,
                                          actions, gbih, gbhh, eps,
                                          w1p, w2p, w3p, w4p, wfcp,
                                          gWhhp, gWzp, gWpop, gWprp, GIAb, gEpsb);

  // encoder: NHWC implicit-GEMM MFMA convs (BM=128, swizzled dbuf)
  convN_mfma<4,64,32,32,32,10>  <<< dim3(Nimg*1024/128, 1), 256, 0, stream >>>(statesB, w1p, c1_b, act1);
  convN_mfma<32,32,64,16,64,8>  <<< dim3(Nimg*256/128, 1), 256, 0, stream >>>(act1, w2p, c2_b, act2);
  convN_mfma<64,16,128,8,128,6> <<< dim3(Nimg*64/128, 1), 256, 0, stream >>>(act2, w3p, c3_b, act3);
  convN_mfma<128,8,256,4,128,4> <<< dim3(Nimg*16/128, 2), 256, 0, stream >>>(act3, w4p, c4_b, act4);

  fc_mfma2<<< dim3(Nimg/64, 4), 256, 0, stream >>>(act4, wfcp, fc_b, feats);
  feats_pack<<< 2048, 256, 0, stream >>>(feats, gFA);

  rssm_mfma<<< 2, 512, 0, stream >>>(gWhhp, gWzp, gWpop, gWprp, gFA,
                                     GIAb, gEpsb, gbhh, pr_b, po_b, (float*)d_out);
}

// Round 3
// 572.701 us; speedup vs baseline: 1.0279x; 1.0279x over previous
//
#include <hip/hip_runtime.h>
#include <math.h>

#define Bn 32
#define Tn 64
#define An 6
#define Ln 32
#define Hn 128
#define FDn 256
#define Nimg (Bn*Tn)   // 2048

typedef __attribute__((ext_vector_type(8))) short frag_ab;     // 8 bf16
typedef __attribute__((ext_vector_type(4))) float frag_cd;     // 4 fp32
typedef _Float16 h2_t __attribute__((ext_vector_type(2)));

__device__ __forceinline__ float sigmoid_fast(float x){
  return __builtin_amdgcn_rcpf(1.f + __expf(-x));
}
__device__ __forceinline__ float tanh_fast(float x){
  float x2 = fminf(fmaxf(2.f*x, -30.f), 30.f);
  float e = __expf(x2);
  return (e - 1.f) * __builtin_amdgcn_rcpf(e + 1.f);
}

__device__ __forceinline__ unsigned short f2bf(float f){
  unsigned int u = __float_as_uint(f);
  unsigned int r = (u + 0x7fffu + ((u >> 16) & 1u)) >> 16;
  return (unsigned short)r;
}
__device__ __forceinline__ unsigned packh(float a, float b){
  union { h2_t h; unsigned u; } x;
  x.h = (h2_t){(_Float16)a, (_Float16)b};
  return x.u;
}
__device__ __forceinline__ float fdot2u(unsigned a, unsigned b, float c){
  union { unsigned u; h2_t h; } ua, ub;
  ua.u = a; ub.u = b;
#if __has_builtin(__builtin_amdgcn_fdot2)
  return __builtin_amdgcn_fdot2(ua.h, ub.h, c, false);
#else
  return c + (float)ua.h.x*(float)ub.h.x + (float)ua.h.y*(float)ub.h.y;
#endif
}
// barrier without vmcnt drain: global loads/stores in flight stay in flight
#define BAR_LDS() asm volatile("s_waitcnt lgkmcnt(0)\n\ts_barrier" ::: "memory")

// LDS fragment addressing with XOR row swizzle (units: unsigned short)
__device__ __forceinline__ int swz_w(int r, int p){
  return ((r >> 4) << 9) + (p << 7) + ((((r & 15) ^ (p << 2))) << 3);
}
__device__ __forceinline__ int swz_r(int f, int l){
  return (f << 9) + ((l >> 4) << 7) + ((((l & 15) ^ ((l >> 4) << 2))) << 3);
}

// ---------------------------------------------------------------------------
// states: (2048, 3, 64, 64) fp32 NCHW -> (2048, 64, 64, 4) bf16 NHWC (c3 = 0)
// ---------------------------------------------------------------------------
__global__ void __launch_bounds__(256)
states_nhwc_kernel(const float* __restrict__ src, unsigned short* __restrict__ dst)
{
  int idx = blockIdx.x*256 + threadIdx.x;      // 2048*4096
  int n = idx >> 12, pix = idx & 4095;
  const float* s = src + (size_t)n*3*4096 + pix;
  union { unsigned short e[4]; uint2 v; } u;
  u.e[0] = f2bf(s[0]); u.e[1] = f2bf(s[4096]); u.e[2] = f2bf(s[8192]); u.e[3] = 0;
  *(uint2*)(dst + (size_t)idx*4) = u.v;
}

// ---------------------------------------------------------------------------
// merged prep: conv/fc weight permute->bf16 (tap-major, c-fast) + scan weight
// f16-pair packs for the SGPR-broadcast scan:
//   g_whh2 [c(64)][n(384)] : Whh row n, k-pair c
//   g_wihz [c(16)][n(384)] : Wih z-part (k 0..31)
//   g_pr2  [c(64)][o(64)]  : prior rows, k-pair c
//   g_po2  [c(64)][o(64)]  : post h-part rows, k-pair c
// ---------------------------------------------------------------------------
__global__ void __launch_bounds__(256)
prep2_kernel(const float* __restrict__ c1w, const float* __restrict__ c2w,
             const float* __restrict__ c3w, const float* __restrict__ c4w,
             const float* __restrict__ fcw,
             const float* __restrict__ gwhh, const float* __restrict__ gwih,
             const float* __restrict__ prw,  const float* __restrict__ pow_,
             unsigned short* __restrict__ w1p, unsigned short* __restrict__ w2p,
             unsigned short* __restrict__ w3p, unsigned short* __restrict__ w4p,
             unsigned short* __restrict__ wfcp,
             unsigned* __restrict__ g_whh2, unsigned* __restrict__ g_wihz,
             unsigned* __restrict__ g_pr2,  unsigned* __restrict__ g_po2)
{
  const int bid = blockIdx.x, tid = threadIdx.x;
  if (bid < 128){            // c2: (64,32,16) -> [k][tap*32+c]
    int idx = bid*256+tid;
    int k = idx >> 9, r = idx & 511, tap = r >> 5, c = r & 31;
    w2p[idx] = f2bf(c2w[k*512 + c*16 + tap]);
  } else if (bid < 640){     // c3: (128,64,16)
    int idx = (bid-128)*256+tid;
    int k = idx >> 10, r = idx & 1023, tap = r >> 6, c = r & 63;
    w3p[idx] = f2bf(c3w[k*1024 + c*16 + tap]);
  } else if (bid < 2688){    // c4: (256,128,16)
    int idx = (bid-640)*256+tid;
    int k = idx >> 11, r = idx & 2047, tap = r >> 7, c = r & 127;
    w4p[idx] = f2bf(c4w[k*2048 + c*16 + tap]);
  } else if (bid < 6784){    // fc: [o][sp*256+c] = src[o*4096 + c*16 + sp]
    int idx = (bid-2688)*256+tid;
    int o = idx >> 12, r = idx & 4095, sp = r >> 8, c = r & 255;
    wfcp[idx] = f2bf(fcw[o*4096 + c*16 + sp]);
  } else if (bid < 6792){    // c1: (32,3,16) -> [k][tap*4+c], c3=0
    int idx = (bid-6784)*256+tid;
    int k = idx >> 6, r = idx & 63, tap = r >> 2, c = r & 3;
    w1p[idx] = (c < 3) ? f2bf(c1w[k*48 + c*16 + tap]) : (unsigned short)0;
  } else if (bid < 6888){    // whh pack: 24576 uints, [c][n]
    int idx = (bid-6792)*256+tid;
    int c = idx / 384, i = idx - c*384;
    g_whh2[idx] = packh(gwhh[i*128 + 2*c], gwhh[i*128 + 2*c + 1]);
  } else if (bid < 6912){    // wih z-part pack: 6144 uints, [c][n]
    int idx = (bid-6888)*256+tid;
    int c = idx / 384, i = idx - c*384;
    g_wihz[idx] = packh(gwih[i*38 + 2*c], gwih[i*38 + 2*c + 1]);
  } else if (bid < 6928){    // prior pack: 4096 uints, [c][o]
    int idx = (bid-6912)*256+tid;
    int c = idx >> 6, o = idx & 63;
    g_pr2[idx] = packh(prw[o*128 + 2*c], prw[o*128 + 2*c + 1]);
  } else {                   // post h-part pack: 4096 uints, [c][o]
    int idx = (bid-6928)*256+tid;
    int c = idx >> 6, o = idx & 63;
    g_po2[idx] = packh(pow_[o*384 + 2*c], pow_[o*384 + 2*c + 1]);
  }
}

// GIA[bt][n] = bih[n] + a_t . Wih_a[n]   (f32, no recurrence)
__global__ void __launch_bounds__(384)
gia_kernel(const float* __restrict__ actions, const float* __restrict__ gwih,
           const float* __restrict__ bih, float* __restrict__ GIA)
{
  const int tid = threadIdx.x;
  const int bt0 = blockIdx.x * 8;
  __shared__ float ash[48];
  if (tid < 48) ash[tid] = actions[(size_t)bt0*6 + tid];
  float w6[6];
#pragma unroll
  for (int k = 0; k < 6; k++) w6[k] = gwih[tid*38 + 32 + k];
  const float bv = bih[tid];
  __syncthreads();
#pragma unroll
  for (int r = 0; r < 8; r++){
    float v = bv;
#pragma unroll
    for (int k = 0; k < 6; k++) v = fmaf(ash[r*6+k], w6[k], v);
    GIA[(size_t)(bt0 + r)*384 + tid] = v;
  }
}

// POF[bt][o] = po_b[o] + Wpo_f[o] . f_bt   (f32 GEMM 2048x64x256, no recurrence)
__global__ void __launch_bounds__(256)
pof_kernel(const float* __restrict__ feats, const float* __restrict__ po_w,
           const float* __restrict__ po_b, float* __restrict__ POF)
{
  const int tid = threadIdx.x;
  const int bt0 = blockIdx.x * 8;
  __shared__ __align__(16) float fsh[8*256];
  const float4* fsrc = (const float4*)(feats + (size_t)bt0*256);
  ((float4*)fsh)[tid]       = fsrc[tid];
  ((float4*)fsh)[tid + 256] = fsrc[tid + 256];
  __syncthreads();
  const float4* w4 = (const float4*)po_w;
  const float4* f4 = (const float4*)fsh;
#pragma unroll
  for (int i = 0; i < 2; i++){
    int item = tid + i*256;
    int row = item >> 6, o = item & 63;
    float4 acc = {0.f,0.f,0.f,0.f};
#pragma unroll 8
    for (int k = 0; k < 64; k++){
      float4 wv = w4[o*96 + 32 + k];
      float4 fv = f4[row*64 + k];
      acc.x = fmaf(wv.x, fv.x, acc.x);
      acc.y = fmaf(wv.y, fv.y, acc.y);
      acc.z = fmaf(wv.z, fv.z, acc.z);
      acc.w = fmaf(wv.w, fv.w, acc.w);
    }
    POF[(size_t)(bt0 + row)*64 + o] = (acc.x + acc.y) + (acc.z + acc.w) + po_b[o];
  }
}

// ---------------------------------------------------------------------------
// NHWC implicit-GEMM conv (k=4, s=2, p=1), MFMA 16x16x32 bf16.  (unchanged)
// ---------------------------------------------------------------------------
template<int Cin, int IN, int Kout, int OUT, int BN, int LOG_SPB>
__global__ void __launch_bounds__(256)
convN_mfma(const unsigned short* __restrict__ in,
           const unsigned short* __restrict__ wB,
           const float* __restrict__ bias,
           unsigned short* __restrict__ out)
{
  constexpr int SPB = OUT*OUT;
  constexpr int KD  = 16*Cin;
  constexpr int NCH = KD/32;
  constexpr int NFN = BN/32;
  constexpr int BFR = BN/16;
  constexpr int BSL = (BN*4 + 255)/256;
  __shared__ __align__(16) unsigned short Alds[2][8*512];
  __shared__ __align__(16) unsigned short Blds[2][BFR*512];

  const int tid = threadIdx.x;
  const int wave = tid >> 6, lane = tid & 63;
  const unsigned m0 = blockIdx.x * 128;
  const int n0 = blockIdx.y * BN;

  const int p = tid & 3;
  const unsigned short* baseA[2]; int oyA[2], oxA[2]; int AdstI[2];
#pragma unroll
  for (int h = 0; h < 2; h++){
    int r = (tid >> 2) + h*64;
    unsigned m = m0 + r;
    int nimg = m >> LOG_SPB;
    int sp = m & (SPB - 1);
    oyA[h] = sp / OUT; oxA[h] = sp & (OUT - 1);
    baseA[h] = in + (size_t)nimg * IN * IN * Cin;
    AdstI[h] = swz_w(r, p);
  }

  const unsigned short* BsrcH[BSL]; int BdstIH[BSL]; bool bActH[BSL];
#pragma unroll
  for (int h = 0; h < BSL; h++){
    int bn = (tid >> 2) + h*64, pb = tid & 3;
    bActH[h] = bn < BN;
    BsrcH[h] = wB + (size_t)(n0 + bn)*KD + pb*8;
    BdstIH[h] = swz_w(bn, pb);
  }

  const int mhalf = wave >> 1, nhalf = wave & 1;
  frag_cd acc[4][NFN];
#pragma unroll
  for (int i = 0; i < 4; i++)
#pragma unroll
    for (int j = 0; j < NFN; j++) acc[i][j] = (frag_cd){0.f,0.f,0.f,0.f};

  auto loadA = [&](int kt, int h) -> uint4 {
    if constexpr (Cin >= 32){
      constexpr int CPT = Cin/32;
      int tap = kt / CPT;
      int c0 = (kt - tap*CPT)*32;
      int kh = tap >> 2, kw = tap & 3;
      int iy = 2*oyA[h] - 1 + kh;
      int ix = 2*oxA[h] - 1 + kw;
      uint4 v = {0u,0u,0u,0u};
      if ((unsigned)iy < (unsigned)IN && (unsigned)ix < (unsigned)IN)
        v = *(const uint4*)(baseA[h] + ((iy*IN + ix)*Cin + c0 + p*8));
      return v;
    } else {
      int kh = kt*2 + (p >> 1);
      int kw0 = (p & 1)*2;
      int iy = 2*oyA[h] - 1 + kh;
      int ix0 = 2*oxA[h] - 1 + kw0;
      union { uint2 u2[2]; uint4 u4; } v; v.u4 = (uint4){0u,0u,0u,0u};
      bool iyok = (unsigned)iy < (unsigned)IN;
      const unsigned short* rowp = baseA[h] + iy*IN*4;
#pragma unroll
      for (int d = 0; d < 2; d++){
        int ix = ix0 + d;
        if (iyok && (unsigned)ix < (unsigned)IN) v.u2[d] = *(const uint2*)(rowp + ix*4);
      }
      return v.u4;
    }
  };

  const int rdoff = swz_r(0, lane);

  uint4 aR0 = loadA(0,0), aR1 = loadA(0,1);
  uint4 bR[BSL];
#pragma unroll
  for (int h = 0; h < BSL; h++)
    bR[h] = bActH[h] ? *(const uint4*)BsrcH[h] : (uint4){0u,0u,0u,0u};
  *(uint4*)&Alds[0][AdstI[0]] = aR0;
  *(uint4*)&Alds[0][AdstI[1]] = aR1;
#pragma unroll
  for (int h = 0; h < BSL; h++)
    if (bActH[h]) *(uint4*)&Blds[0][BdstIH[h]] = bR[h];
  if (NCH > 1){
    aR0 = loadA(1,0); aR1 = loadA(1,1);
#pragma unroll
    for (int h = 0; h < BSL; h++)
      if (bActH[h]) bR[h] = *(const uint4*)(BsrcH[h] + 32);
  }
  BAR_LDS();

#pragma unroll 2
  for (int kt = 0; kt < NCH; kt++){
    const int cur = kt & 1, nxt = cur ^ 1;
    if (kt + 1 < NCH){
      *(uint4*)&Alds[nxt][AdstI[0]] = aR0;
      *(uint4*)&Alds[nxt][AdstI[1]] = aR1;
#pragma unroll
      for (int h = 0; h < BSL; h++)
        if (bActH[h]) *(uint4*)&Blds[nxt][BdstIH[h]] = bR[h];
      if (kt + 2 < NCH){
        aR0 = loadA(kt+2, 0);
        aR1 = loadA(kt+2, 1);
#pragma unroll
        for (int h = 0; h < BSL; h++)
          if (bActH[h]) bR[h] = *(const uint4*)(BsrcH[h] + (kt+2)*32);
      }
    }
    frag_ab a[4], bf[NFN];
#pragma unroll
    for (int i = 0; i < 4; i++)
      a[i] = *(const frag_ab*)&Alds[cur][(((mhalf<<2) + i) << 9) + rdoff];
#pragma unroll
    for (int j = 0; j < NFN; j++)
      bf[j] = *(const frag_ab*)&Blds[cur][((nhalf*NFN + j) << 9) + rdoff];
#pragma unroll
    for (int i = 0; i < 4; i++)
#pragma unroll
      for (int j = 0; j < NFN; j++)
        acc[i][j] = __builtin_amdgcn_mfma_f32_16x16x32_bf16(a[i], bf[j], acc[i][j], 0, 0, 0);
    BAR_LDS();
  }

  const unsigned mb = m0 + mhalf*64 + ((lane >> 4) << 2);
#pragma unroll
  for (int j = 0; j < NFN; j++){
    const int kg = n0 + nhalf*(NFN*16) + j*16 + (lane & 15);
    const float bv = bias[kg];
#pragma unroll
    for (int i = 0; i < 4; i++){
#pragma unroll
      for (int r = 0; r < 4; r++){
        unsigned mg = mb + i*16 + r;
        out[(size_t)mg*Kout + kg] = f2bf(fmaxf(acc[i][j][r] + bv, 0.f));
      }
    }
  }
}

// ---------------------------------------------------------------------------
// FC GEMM: A (2048 x 4096) bf16, W (256 x 4096) permuted.  (unchanged)
// ---------------------------------------------------------------------------
__global__ void __launch_bounds__(256)
fc_mfma2(const unsigned short* __restrict__ A, const unsigned short* __restrict__ wB,
         const float* __restrict__ bias, float* __restrict__ outF)
{
  constexpr int KD = 4096, NCH = KD/32;
  __shared__ __align__(16) unsigned short Alds[2][4*512];
  __shared__ __align__(16) unsigned short Blds[2][4*512];

  const int tid = threadIdx.x, wave = tid >> 6, lane = tid & 63;
  const int m0 = blockIdx.x * 64, n0 = blockIdx.y * 64;
  const int r = tid >> 2, pc = tid & 3;
  const unsigned short* Asrc = A + (size_t)(m0 + r)*KD + pc*8;
  const unsigned short* Bsrc = wB + (size_t)(n0 + r)*KD + pc*8;
  const int wI = swz_w(r, pc);
  const int mh = wave >> 1, nh = wave & 1;
  const int rdoff = swz_r(0, lane);

  frag_cd acc[2][2];
#pragma unroll
  for (int i = 0; i < 2; i++)
#pragma unroll
    for (int j = 0; j < 2; j++) acc[i][j] = (frag_cd){0.f,0.f,0.f,0.f};

  uint4 aP = *(const uint4*)Asrc, bP = *(const uint4*)Bsrc;
  *(uint4*)&Alds[0][wI] = aP;
  *(uint4*)&Blds[0][wI] = bP;
  aP = *(const uint4*)(Asrc + 32);
  bP = *(const uint4*)(Bsrc + 32);
  BAR_LDS();

#pragma unroll 2
  for (int kt = 0; kt < NCH; kt++){
    const int cur = kt & 1, nxt = cur ^ 1;
    if (kt + 1 < NCH){
      *(uint4*)&Alds[nxt][wI] = aP;
      *(uint4*)&Blds[nxt][wI] = bP;
      if (kt + 2 < NCH){
        aP = *(const uint4*)(Asrc + (kt+2)*32);
        bP = *(const uint4*)(Bsrc + (kt+2)*32);
      }
    }
    frag_ab a[2], b[2];
#pragma unroll
    for (int i = 0; i < 2; i++) a[i] = *(const frag_ab*)&Alds[cur][(((mh<<1)+i) << 9) + rdoff];
#pragma unroll
    for (int j = 0; j < 2; j++) b[j] = *(const frag_ab*)&Blds[cur][(((nh<<1)+j) << 9) + rdoff];
#pragma unroll
    for (int i = 0; i < 2; i++)
#pragma unroll
      for (int j = 0; j < 2; j++)
        acc[i][j] = __builtin_amdgcn_mfma_f32_16x16x32_bf16(a[i], b[j], acc[i][j], 0, 0, 0);
    BAR_LDS();
  }

  const int mb = m0 + mh*32 + ((lane >> 4) << 2);
#pragma unroll
  for (int j = 0; j < 2; j++){
    const int kg = n0 + nh*32 + j*16 + (lane & 15);
    const float bv = bias[kg];
#pragma unroll
    for (int i = 0; i < 2; i++)
#pragma unroll
      for (int rr = 0; rr < 4; rr++)
        outF[(size_t)(mb + i*16 + rr)*256 + kg] = acc[i][j][rr] + bv;
  }
}

// ---------------------------------------------------------------------------
// RSSM scan v6: 32 blocks (one batch elem each) x 384 threads (6 waves).
// Key change vs v4: the h-vector is broadcast ONCE per wave per step via
// 1 ds_read_b32 + 64 v_readlane into wave-uniform registers; all matvecs
// (gh / prior / post-h) then run as v_dot2 with a scalar h operand — the
// LDS pipe (previously ~2700 cy/step of broadcast reads) is nearly idle.
// No-recurrence parts hoisted: GIA = bih + a.Wih_a (f32), POF = po_b +
// Wpo_f.f (f32) — the scan never touches feats/actions.
// Phase C wave-specialized: wave0 = prior (64 full dots), wave1 = post-h +
// z-sample (mu/lv paired via shfl_xor 32), waves 2-5 refill h regs only.
// ---------------------------------------------------------------------------
__global__ void __launch_bounds__(384)
rssm_scan5(const unsigned* __restrict__ g_whh2, const unsigned* __restrict__ g_wihz,
           const unsigned* __restrict__ g_pr2,  const unsigned* __restrict__ g_po2,
           const float* __restrict__ GIA, const float* __restrict__ POF,
           const float* __restrict__ eps, const float* __restrict__ bhh,
           const float* __restrict__ pr_b, float* __restrict__ out)
{
  __shared__ __align__(16) _Float16 sh_h[128];
  __shared__ __align__(16) _Float16 sh_z[32];
  __shared__ float sh_gi[384];
  __shared__ float sh_gh[384];

  const int b = blockIdx.x, tid = threadIdx.x;
  const int wv = tid >> 6, lane = tid & 63;

  unsigned whh2[64];
#pragma unroll
  for (int c = 0; c < 64; c++) whh2[c] = g_whh2[c*384 + tid];
  unsigned wihz[16];
#pragma unroll
  for (int c = 0; c < 16; c++) wihz[c] = g_wihz[c*384 + tid];
  const float bhh_i = bhh[tid];

  unsigned wpx[64];
  float prbr = 0.f;
  if (wv == 0){
#pragma unroll
    for (int c = 0; c < 64; c++) wpx[c] = g_pr2[c*64 + lane];
    prbr = pr_b[lane];
  } else if (wv == 1){
#pragma unroll
    for (int c = 0; c < 64; c++) wpx[c] = g_po2[c*64 + lane];
  }

  unsigned hsu[64];
#pragma unroll
  for (int c = 0; c < 64; c++) hsu[c] = 0u;

  if (tid < 128) sh_h[tid] = (_Float16)0.f;
  if (tid < 32)  sh_z[tid] = (_Float16)0.f;

  float GIAr = GIA[(size_t)(b*64)*384 + tid];
  float POFr = (wv == 1) ? POF[(size_t)(b*64)*64 + lane] : 0.f;
  float epsr = (wv == 1 && lane < 32) ? eps[(size_t)(b*64)*32 + lane] : 0.f;

  const int OFF_MUP = 0;
  const int OFF_LVP = Bn*Tn*Ln;
  const int OFF_MUQ = 2*Bn*Tn*Ln;
  const int OFF_LVQ = 3*Bn*Tn*Ln;
  const int OFF_H   = 4*Bn*Tn*Ln;
  const int OFF_Z   = 4*Bn*Tn*Ln + Bn*Tn*Hn;

  float hreg = 0.f;
  __syncthreads();

  for (int t = 0; t < Tn; t++){
    const size_t bt = (size_t)b*64 + t;

    // ---- phase A: gi (GIA + z-dot, LDS) and gh (scalar-h dot, no LDS) ----
    {
      const uint4* Z4 = (const uint4*)sh_z;
      uint4 z0 = Z4[0], z1 = Z4[1], z2 = Z4[2], z3 = Z4[3];
      float a0 = GIAr, a1 = 0.f, a2 = 0.f, a3 = 0.f;
      a0 = fdot2u(wihz[0],  z0.x, a0); a1 = fdot2u(wihz[1],  z0.y, a1);
      a2 = fdot2u(wihz[2],  z0.z, a2); a3 = fdot2u(wihz[3],  z0.w, a3);
      a0 = fdot2u(wihz[4],  z1.x, a0); a1 = fdot2u(wihz[5],  z1.y, a1);
      a2 = fdot2u(wihz[6],  z1.z, a2); a3 = fdot2u(wihz[7],  z1.w, a3);
      a0 = fdot2u(wihz[8],  z2.x, a0); a1 = fdot2u(wihz[9],  z2.y, a1);
      a2 = fdot2u(wihz[10], z2.z, a2); a3 = fdot2u(wihz[11], z2.w, a3);
      a0 = fdot2u(wihz[12], z3.x, a0); a1 = fdot2u(wihz[13], z3.y, a1);
      a2 = fdot2u(wihz[14], z3.z, a2); a3 = fdot2u(wihz[15], z3.w, a3);

      float g0 = bhh_i, g1 = 0.f, g2 = 0.f, g3 = 0.f;
#pragma unroll
      for (int c = 0; c < 64; c += 4){
        g0 = fdot2u(whh2[c],   hsu[c],   g0);
        g1 = fdot2u(whh2[c+1], hsu[c+1], g1);
        g2 = fdot2u(whh2[c+2], hsu[c+2], g2);
        g3 = fdot2u(whh2[c+3], hsu[c+3], g3);
      }
      sh_gi[tid] = (a0 + a1) + (a2 + a3);
      sh_gh[tid] = (g0 + g1) + (g2 + g3);
    }
    if (t < Tn-1) GIAr = GIA[(bt+1)*384 + tid];
    BAR_LDS();

    // ---- phase B: gates (threads 0..127) ----
    if (tid < 128){
      const float r  = sigmoid_fast(sh_gi[tid]       + sh_gh[tid]);
      const float zg = sigmoid_fast(sh_gi[128 + tid] + sh_gh[128 + tid]);
      const float nn = tanh_fast(fmaf(r, sh_gh[256 + tid], sh_gi[256 + tid]));
      hreg = (1.f - zg)*nn + zg*hreg;
      sh_h[tid] = (_Float16)hreg;
      out[OFF_H + bt*128 + tid] = hreg;
    }
    BAR_LDS();

    // ---- phase C: refill uniform h; wave0 prior; wave1 post + z ----
    {
      unsigned hv = ((const unsigned*)sh_h)[lane];
#pragma unroll
      for (int c = 0; c < 64; c++) hsu[c] = __builtin_amdgcn_readlane(hv, c);
    }
    if (wv == 0){
      float p0 = prbr, p1 = 0.f, p2 = 0.f, p3 = 0.f;
#pragma unroll
      for (int c = 0; c < 64; c += 4){
        p0 = fdot2u(wpx[c],   hsu[c],   p0);
        p1 = fdot2u(wpx[c+1], hsu[c+1], p1);
        p2 = fdot2u(wpx[c+2], hsu[c+2], p2);
        p3 = fdot2u(wpx[c+3], hsu[c+3], p3);
      }
      const float p = (p0 + p1) + (p2 + p3);
      if (lane < 32) out[OFF_MUP + bt*32 + lane] = p;
      else           out[OFF_LVP + bt*32 + (lane - 32)] = p;
    } else if (wv == 1){
      float p0 = POFr, p1 = 0.f, p2 = 0.f, p3 = 0.f;
#pragma unroll
      for (int c = 0; c < 64; c += 4){
        p0 = fdot2u(wpx[c],   hsu[c],   p0);
        p1 = fdot2u(wpx[c+1], hsu[c+1], p1);
        p2 = fdot2u(wpx[c+2], hsu[c+2], p2);
        p3 = fdot2u(wpx[c+3], hsu[c+3], p3);
      }
      const float p = (p0 + p1) + (p2 + p3);
      const float q = __shfl_xor(p, 32);
      if (lane < 32){
        out[OFF_MUQ + bt*32 + lane] = p;
        const float zz = fmaf(__expf(0.5f*q), epsr, p);
        sh_z[lane] = (_Float16)zz;
        out[OFF_Z + bt*32 + lane] = zz;
      } else {
        out[OFF_LVQ + bt*32 + (lane - 32)] = p;
      }
      if (t < Tn-1){
        POFr = POF[(bt+1)*64 + lane];
        if (lane < 32) epsr = eps[(bt+1)*32 + lane];
      }
    }
    BAR_LDS();
  }
}

// ---------------------------------------------------------------------------
extern "C" void kernel_launch(void* const* d_in, const int* in_sizes, int n_in,
                              void* d_out, int out_size, void* d_ws, size_t ws_size,
                              hipStream_t stream)
{
  const float* states = (const float*)d_in[0];
  const float* actions= (const float*)d_in[1];
  const float* c1_w = (const float*)d_in[2];  const float* c1_b = (const float*)d_in[3];
  const float* c2_w = (const float*)d_in[4];  const float* c2_b = (const float*)d_in[5];
  const float* c3_w = (const float*)d_in[6];  const float* c3_b = (const float*)d_in[7];
  const float* c4_w = (const float*)d_in[8];  const float* c4_b = (const float*)d_in[9];
  const float* fc_w = (const float*)d_in[10]; const float* fc_b = (const float*)d_in[11];
  const float* gwih = (const float*)d_in[12]; const float* gwhh = (const float*)d_in[13];
  const float* gbih = (const float*)d_in[14]; const float* gbhh = (const float*)d_in[15];
  const float* pr_w = (const float*)d_in[16]; const float* pr_b = (const float*)d_in[17];
  const float* po_w = (const float*)d_in[18]; const float* po_b = (const float*)d_in[19];
  const float* eps  = (const float*)d_in[20];

  char* p = (char*)d_ws;
  auto alloc = [&](size_t bytes){ char* r = p; p += (bytes + 255) & ~255ULL; return r; };

  unsigned short* statesB = (unsigned short*)alloc((size_t)Nimg*4096*4*2); // NHWC c=4
  unsigned short* act1    = (unsigned short*)alloc((size_t)Nimg*1024*32*2);
  unsigned short* act2    = (unsigned short*)alloc((size_t)Nimg*256*64*2);
  unsigned short* act3    = (unsigned short*)alloc((size_t)Nimg*64*128*2);
  unsigned short* act4    = (unsigned short*)alloc((size_t)Nimg*16*256*2);
  float*          feats   = (float*)alloc((size_t)Nimg*FDn*4);
  unsigned short* w1p     = (unsigned short*)alloc(32*64*2);
  unsigned short* w2p     = (unsigned short*)alloc((size_t)64*512*2);
  unsigned short* w3p     = (unsigned short*)alloc((size_t)128*1024*2);
  unsigned short* w4p     = (unsigned short*)alloc((size_t)256*2048*2);
  unsigned short* wfcp    = (unsigned short*)alloc((size_t)256*4096*2);
  unsigned* g_whh2 = (unsigned*)alloc((size_t)24576*4);
  unsigned* g_wihz = (unsigned*)alloc((size_t)6144*4);
  unsigned* g_pr2  = (unsigned*)alloc((size_t)4096*4);
  unsigned* g_po2  = (unsigned*)alloc((size_t)4096*4);
  float*    GIAb   = (float*)alloc((size_t)786432*4);
  float*    POFb   = (float*)alloc((size_t)Nimg*64*4);

  states_nhwc_kernel<<<Nimg*4096/256, 256, 0, stream>>>(states, statesB);
  prep2_kernel<<<6944, 256, 0, stream>>>(c1_w, c2_w, c3_w, c4_w, fc_w,
                                         gwhh, gwih, pr_w, po_w,
                                         w1p, w2p, w3p, w4p, wfcp,
                                         g_whh2, g_wihz, g_pr2, g_po2);
  gia_kernel<<<Nimg/8, 384, 0, stream>>>(actions, gwih, gbih, GIAb);

  // encoder: NHWC implicit-GEMM MFMA convs (BM=128, swizzled dbuf)
  convN_mfma<4,64,32,32,32,10>  <<< dim3(Nimg*1024/128, 1), 256, 0, stream >>>(statesB, w1p, c1_b, act1);
  convN_mfma<32,32,64,16,64,8>  <<< dim3(Nimg*256/128, 1), 256, 0, stream >>>(act1, w2p, c2_b, act2);
  convN_mfma<64,16,128,8,128,6> <<< dim3(Nimg*64/128, 1), 256, 0, stream >>>(act2, w3p, c3_b, act3);
  convN_mfma<128,8,256,4,128,4> <<< dim3(Nimg*16/128, 2), 256, 0, stream >>>(act3, w4p, c4_b, act4);

  fc_mfma2<<< dim3(Nimg/64, 4), 256, 0, stream >>>(act4, wfcp, fc_b, feats);
  pof_kernel<<< Nimg/8, 256, 0, stream >>>(feats, po_w, po_b, POFb);

  rssm_scan5<<< Bn, 384, 0, stream >>>(g_whh2, g_wihz, g_pr2, g_po2,
                                       GIAb, POFb, eps, gbhh, pr_b, (float*)d_out);
}

// Round 4
// 569.176 us; speedup vs baseline: 1.0342x; 1.0062x over previous
//
#include <hip/hip_runtime.h>
#include <math.h>

#define Bn 32
#define Tn 64
#define An 6
#define Ln 32
#define Hn 128
#define FDn 256
#define Nimg (Bn*Tn)   // 2048

typedef __attribute__((ext_vector_type(8))) short frag_ab;     // 8 bf16
typedef __attribute__((ext_vector_type(4))) float frag_cd;     // 4 fp32
typedef _Float16 h2_t __attribute__((ext_vector_type(2)));

__device__ __forceinline__ float sigmoid_fast(float x){
  return __builtin_amdgcn_rcpf(1.f + __expf(-x));
}
__device__ __forceinline__ float tanh_fast(float x){
  float x2 = fminf(fmaxf(2.f*x, -30.f), 30.f);
  float e = __expf(x2);
  return (e - 1.f) * __builtin_amdgcn_rcpf(e + 1.f);
}

__device__ __forceinline__ unsigned short f2bf(float f){
  unsigned int u = __float_as_uint(f);
  unsigned int r = (u + 0x7fffu + ((u >> 16) & 1u)) >> 16;
  return (unsigned short)r;
}
__device__ __forceinline__ unsigned packh(float a, float b){
  union { h2_t h; unsigned u; } x;
  x.h = (h2_t){(_Float16)a, (_Float16)b};
  return x.u;
}
__device__ __forceinline__ float fdot2u(unsigned a, unsigned b, float c){
  union { unsigned u; h2_t h; } ua, ub;
  ua.u = a; ub.u = b;
#if __has_builtin(__builtin_amdgcn_fdot2)
  return __builtin_amdgcn_fdot2(ua.h, ub.h, c, false);
#else
  return c + (float)ua.h.x*(float)ub.h.x + (float)ua.h.y*(float)ub.h.y;
#endif
}
// barrier without vmcnt drain: global loads/stores in flight stay in flight
#define BAR_LDS() asm volatile("s_waitcnt lgkmcnt(0)\n\ts_barrier" ::: "memory")

// LDS fragment addressing with XOR row swizzle (units: unsigned short)
__device__ __forceinline__ int swz_w(int r, int p){
  return ((r >> 4) << 9) + (p << 7) + ((((r & 15) ^ (p << 2))) << 3);
}
__device__ __forceinline__ int swz_r(int f, int l){
  return (f << 9) + ((l >> 4) << 7) + ((((l & 15) ^ ((l >> 4) << 2))) << 3);
}

// ---------------------------------------------------------------------------
// states: (2048, 3, 64, 64) fp32 NCHW -> (2048, 64, 64, 4) bf16 NHWC (c3 = 0)
// ---------------------------------------------------------------------------
__global__ void __launch_bounds__(256)
states_nhwc_kernel(const float* __restrict__ src, unsigned short* __restrict__ dst)
{
  int idx = blockIdx.x*256 + threadIdx.x;      // 2048*4096
  int n = idx >> 12, pix = idx & 4095;
  const float* s = src + (size_t)n*3*4096 + pix;
  union { unsigned short e[4]; uint2 v; } u;
  u.e[0] = f2bf(s[0]); u.e[1] = f2bf(s[4096]); u.e[2] = f2bf(s[8192]); u.e[3] = 0;
  *(uint2*)(dst + (size_t)idx*4) = u.v;
}

// ---------------------------------------------------------------------------
// merged prep: conv/fc weight permute->bf16 (tap-major, c-fast) + scan weight
// f16-pair packs for the SGPR-broadcast scan:
//   g_whh2 [c(64)][n(384)] : Whh row n, k-pair c
//   g_wihz [c(16)][n(384)] : Wih z-part (k 0..31)
//   g_pr2  [c(64)][o(64)]  : prior rows, k-pair c
//   g_po2  [c(64)][o(64)]  : post h-part rows, k-pair c
// ---------------------------------------------------------------------------
__global__ void __launch_bounds__(256)
prep2_kernel(const float* __restrict__ c1w, const float* __restrict__ c2w,
             const float* __restrict__ c3w, const float* __restrict__ c4w,
             const float* __restrict__ fcw,
             const float* __restrict__ gwhh, const float* __restrict__ gwih,
             const float* __restrict__ prw,  const float* __restrict__ pow_,
             unsigned short* __restrict__ w1p, unsigned short* __restrict__ w2p,
             unsigned short* __restrict__ w3p, unsigned short* __restrict__ w4p,
             unsigned short* __restrict__ wfcp,
             unsigned* __restrict__ g_whh2, unsigned* __restrict__ g_wihz,
             unsigned* __restrict__ g_pr2,  unsigned* __restrict__ g_po2)
{
  const int bid = blockIdx.x, tid = threadIdx.x;
  if (bid < 128){            // c2: (64,32,16) -> [k][tap*32+c]
    int idx = bid*256+tid;
    int k = idx >> 9, r = idx & 511, tap = r >> 5, c = r & 31;
    w2p[idx] = f2bf(c2w[k*512 + c*16 + tap]);
  } else if (bid < 640){     // c3: (128,64,16)
    int idx = (bid-128)*256+tid;
    int k = idx >> 10, r = idx & 1023, tap = r >> 6, c = r & 63;
    w3p[idx] = f2bf(c3w[k*1024 + c*16 + tap]);
  } else if (bid < 2688){    // c4: (256,128,16)
    int idx = (bid-640)*256+tid;
    int k = idx >> 11, r = idx & 2047, tap = r >> 7, c = r & 127;
    w4p[idx] = f2bf(c4w[k*2048 + c*16 + tap]);
  } else if (bid < 6784){    // fc: [o][sp*256+c] = src[o*4096 + c*16 + sp]
    int idx = (bid-2688)*256+tid;
    int o = idx >> 12, r = idx & 4095, sp = r >> 8, c = r & 255;
    wfcp[idx] = f2bf(fcw[o*4096 + c*16 + sp]);
  } else if (bid < 6792){    // c1: (32,3,16) -> [k][tap*4+c], c3=0
    int idx = (bid-6784)*256+tid;
    int k = idx >> 6, r = idx & 63, tap = r >> 2, c = r & 3;
    w1p[idx] = (c < 3) ? f2bf(c1w[k*48 + c*16 + tap]) : (unsigned short)0;
  } else if (bid < 6888){    // whh pack: 24576 uints, [c][n]
    int idx = (bid-6792)*256+tid;
    int c = idx / 384, i = idx - c*384;
    g_whh2[idx] = packh(gwhh[i*128 + 2*c], gwhh[i*128 + 2*c + 1]);
  } else if (bid < 6912){    // wih z-part pack: 6144 uints, [c][n]
    int idx = (bid-6888)*256+tid;
    int c = idx / 384, i = idx - c*384;
    g_wihz[idx] = packh(gwih[i*38 + 2*c], gwih[i*38 + 2*c + 1]);
  } else if (bid < 6928){    // prior pack: 4096 uints, [c][o]
    int idx = (bid-6912)*256+tid;
    int c = idx >> 6, o = idx & 63;
    g_pr2[idx] = packh(prw[o*128 + 2*c], prw[o*128 + 2*c + 1]);
  } else {                   // post h-part pack: 4096 uints, [c][o]
    int idx = (bid-6928)*256+tid;
    int c = idx >> 6, o = idx & 63;
    g_po2[idx] = packh(pow_[o*384 + 2*c], pow_[o*384 + 2*c + 1]);
  }
}

// GIA[bt][n] = bih[n] + a_t . Wih_a[n]   (f32, no recurrence)
__global__ void __launch_bounds__(384)
gia_kernel(const float* __restrict__ actions, const float* __restrict__ gwih,
           const float* __restrict__ bih, float* __restrict__ GIA)
{
  const int tid = threadIdx.x;
  const int bt0 = blockIdx.x * 8;
  __shared__ float ash[48];
  if (tid < 48) ash[tid] = actions[(size_t)bt0*6 + tid];
  float w6[6];
#pragma unroll
  for (int k = 0; k < 6; k++) w6[k] = gwih[tid*38 + 32 + k];
  const float bv = bih[tid];
  __syncthreads();
#pragma unroll
  for (int r = 0; r < 8; r++){
    float v = bv;
#pragma unroll
    for (int k = 0; k < 6; k++) v = fmaf(ash[r*6+k], w6[k], v);
    GIA[(size_t)(bt0 + r)*384 + tid] = v;
  }
}

// POF[bt][o] = po_b[o] + Wpo_f[o] . f_bt   (f32 GEMM 2048x64x256, no recurrence)
__global__ void __launch_bounds__(256)
pof_kernel(const float* __restrict__ feats, const float* __restrict__ po_w,
           const float* __restrict__ po_b, float* __restrict__ POF)
{
  const int tid = threadIdx.x;
  const int bt0 = blockIdx.x * 8;
  __shared__ __align__(16) float fsh[8*256];
  const float4* fsrc = (const float4*)(feats + (size_t)bt0*256);
  ((float4*)fsh)[tid]       = fsrc[tid];
  ((float4*)fsh)[tid + 256] = fsrc[tid + 256];
  __syncthreads();
  const float4* w4 = (const float4*)po_w;
  const float4* f4 = (const float4*)fsh;
#pragma unroll
  for (int i = 0; i < 2; i++){
    int item = tid + i*256;
    int row = item >> 6, o = item & 63;
    float4 acc = {0.f,0.f,0.f,0.f};
#pragma unroll 8
    for (int k = 0; k < 64; k++){
      float4 wv = w4[o*96 + 32 + k];
      float4 fv = f4[row*64 + k];
      acc.x = fmaf(wv.x, fv.x, acc.x);
      acc.y = fmaf(wv.y, fv.y, acc.y);
      acc.z = fmaf(wv.z, fv.z, acc.z);
      acc.w = fmaf(wv.w, fv.w, acc.w);
    }
    POF[(size_t)(bt0 + row)*64 + o] = (acc.x + acc.y) + (acc.z + acc.w) + po_b[o];
  }
}

// ---------------------------------------------------------------------------
// NHWC implicit-GEMM conv (k=4, s=2, p=1), MFMA 16x16x32 bf16.  (unchanged)
// ---------------------------------------------------------------------------
template<int Cin, int IN, int Kout, int OUT, int BN, int LOG_SPB>
__global__ void __launch_bounds__(256)
convN_mfma(const unsigned short* __restrict__ in,
           const unsigned short* __restrict__ wB,
           const float* __restrict__ bias,
           unsigned short* __restrict__ out)
{
  constexpr int SPB = OUT*OUT;
  constexpr int KD  = 16*Cin;
  constexpr int NCH = KD/32;
  constexpr int NFN = BN/32;
  constexpr int BFR = BN/16;
  constexpr int BSL = (BN*4 + 255)/256;
  __shared__ __align__(16) unsigned short Alds[2][8*512];
  __shared__ __align__(16) unsigned short Blds[2][BFR*512];

  const int tid = threadIdx.x;
  const int wave = tid >> 6, lane = tid & 63;
  const unsigned m0 = blockIdx.x * 128;
  const int n0 = blockIdx.y * BN;

  const int p = tid & 3;
  const unsigned short* baseA[2]; int oyA[2], oxA[2]; int AdstI[2];
#pragma unroll
  for (int h = 0; h < 2; h++){
    int r = (tid >> 2) + h*64;
    unsigned m = m0 + r;
    int nimg = m >> LOG_SPB;
    int sp = m & (SPB - 1);
    oyA[h] = sp / OUT; oxA[h] = sp & (OUT - 1);
    baseA[h] = in + (size_t)nimg * IN * IN * Cin;
    AdstI[h] = swz_w(r, p);
  }

  const unsigned short* BsrcH[BSL]; int BdstIH[BSL]; bool bActH[BSL];
#pragma unroll
  for (int h = 0; h < BSL; h++){
    int bn = (tid >> 2) + h*64, pb = tid & 3;
    bActH[h] = bn < BN;
    BsrcH[h] = wB + (size_t)(n0 + bn)*KD + pb*8;
    BdstIH[h] = swz_w(bn, pb);
  }

  const int mhalf = wave >> 1, nhalf = wave & 1;
  frag_cd acc[4][NFN];
#pragma unroll
  for (int i = 0; i < 4; i++)
#pragma unroll
    for (int j = 0; j < NFN; j++) acc[i][j] = (frag_cd){0.f,0.f,0.f,0.f};

  auto loadA = [&](int kt, int h) -> uint4 {
    if constexpr (Cin >= 32){
      constexpr int CPT = Cin/32;
      int tap = kt / CPT;
      int c0 = (kt - tap*CPT)*32;
      int kh = tap >> 2, kw = tap & 3;
      int iy = 2*oyA[h] - 1 + kh;
      int ix = 2*oxA[h] - 1 + kw;
      uint4 v = {0u,0u,0u,0u};
      if ((unsigned)iy < (unsigned)IN && (unsigned)ix < (unsigned)IN)
        v = *(const uint4*)(baseA[h] + ((iy*IN + ix)*Cin + c0 + p*8));
      return v;
    } else {
      int kh = kt*2 + (p >> 1);
      int kw0 = (p & 1)*2;
      int iy = 2*oyA[h] - 1 + kh;
      int ix0 = 2*oxA[h] - 1 + kw0;
      union { uint2 u2[2]; uint4 u4; } v; v.u4 = (uint4){0u,0u,0u,0u};
      bool iyok = (unsigned)iy < (unsigned)IN;
      const unsigned short* rowp = baseA[h] + iy*IN*4;
#pragma unroll
      for (int d = 0; d < 2; d++){
        int ix = ix0 + d;
        if (iyok && (unsigned)ix < (unsigned)IN) v.u2[d] = *(const uint2*)(rowp + ix*4);
      }
      return v.u4;
    }
  };

  const int rdoff = swz_r(0, lane);

  uint4 aR0 = loadA(0,0), aR1 = loadA(0,1);
  uint4 bR[BSL];
#pragma unroll
  for (int h = 0; h < BSL; h++)
    bR[h] = bActH[h] ? *(const uint4*)BsrcH[h] : (uint4){0u,0u,0u,0u};
  *(uint4*)&Alds[0][AdstI[0]] = aR0;
  *(uint4*)&Alds[0][AdstI[1]] = aR1;
#pragma unroll
  for (int h = 0; h < BSL; h++)
    if (bActH[h]) *(uint4*)&Blds[0][BdstIH[h]] = bR[h];
  if (NCH > 1){
    aR0 = loadA(1,0); aR1 = loadA(1,1);
#pragma unroll
    for (int h = 0; h < BSL; h++)
      if (bActH[h]) bR[h] = *(const uint4*)(BsrcH[h] + 32);
  }
  BAR_LDS();

#pragma unroll 2
  for (int kt = 0; kt < NCH; kt++){
    const int cur = kt & 1, nxt = cur ^ 1;
    if (kt + 1 < NCH){
      *(uint4*)&Alds[nxt][AdstI[0]] = aR0;
      *(uint4*)&Alds[nxt][AdstI[1]] = aR1;
#pragma unroll
      for (int h = 0; h < BSL; h++)
        if (bActH[h]) *(uint4*)&Blds[nxt][BdstIH[h]] = bR[h];
      if (kt + 2 < NCH){
        aR0 = loadA(kt+2, 0);
        aR1 = loadA(kt+2, 1);
#pragma unroll
        for (int h = 0; h < BSL; h++)
          if (bActH[h]) bR[h] = *(const uint4*)(BsrcH[h] + (kt+2)*32);
      }
    }
    frag_ab a[4], bf[NFN];
#pragma unroll
    for (int i = 0; i < 4; i++)
      a[i] = *(const frag_ab*)&Alds[cur][(((mhalf<<2) + i) << 9) + rdoff];
#pragma unroll
    for (int j = 0; j < NFN; j++)
      bf[j] = *(const frag_ab*)&Blds[cur][((nhalf*NFN + j) << 9) + rdoff];
#pragma unroll
    for (int i = 0; i < 4; i++)
#pragma unroll
      for (int j = 0; j < NFN; j++)
        acc[i][j] = __builtin_amdgcn_mfma_f32_16x16x32_bf16(a[i], bf[j], acc[i][j], 0, 0, 0);
    BAR_LDS();
  }

  const unsigned mb = m0 + mhalf*64 + ((lane >> 4) << 2);
#pragma unroll
  for (int j = 0; j < NFN; j++){
    const int kg = n0 + nhalf*(NFN*16) + j*16 + (lane & 15);
    const float bv = bias[kg];
#pragma unroll
    for (int i = 0; i < 4; i++){
#pragma unroll
      for (int r = 0; r < 4; r++){
        unsigned mg = mb + i*16 + r;
        out[(size_t)mg*Kout + kg] = f2bf(fmaxf(acc[i][j][r] + bv, 0.f));
      }
    }
  }
}

// ---------------------------------------------------------------------------
// FC GEMM: A (2048 x 4096) bf16, W (256 x 4096) permuted.  (unchanged)
// ---------------------------------------------------------------------------
__global__ void __launch_bounds__(256)
fc_mfma2(const unsigned short* __restrict__ A, const unsigned short* __restrict__ wB,
         const float* __restrict__ bias, float* __restrict__ outF)
{
  constexpr int KD = 4096, NCH = KD/32;
  __shared__ __align__(16) unsigned short Alds[2][4*512];
  __shared__ __align__(16) unsigned short Blds[2][4*512];

  const int tid = threadIdx.x, wave = tid >> 6, lane = tid & 63;
  const int m0 = blockIdx.x * 64, n0 = blockIdx.y * 64;
  const int r = tid >> 2, pc = tid & 3;
  const unsigned short* Asrc = A + (size_t)(m0 + r)*KD + pc*8;
  const unsigned short* Bsrc = wB + (size_t)(n0 + r)*KD + pc*8;
  const int wI = swz_w(r, pc);
  const int mh = wave >> 1, nh = wave & 1;
  const int rdoff = swz_r(0, lane);

  frag_cd acc[2][2];
#pragma unroll
  for (int i = 0; i < 2; i++)
#pragma unroll
    for (int j = 0; j < 2; j++) acc[i][j] = (frag_cd){0.f,0.f,0.f,0.f};

  uint4 aP = *(const uint4*)Asrc, bP = *(const uint4*)Bsrc;
  *(uint4*)&Alds[0][wI] = aP;
  *(uint4*)&Blds[0][wI] = bP;
  aP = *(const uint4*)(Asrc + 32);
  bP = *(const uint4*)(Bsrc + 32);
  BAR_LDS();

#pragma unroll 2
  for (int kt = 0; kt < NCH; kt++){
    const int cur = kt & 1, nxt = cur ^ 1;
    if (kt + 1 < NCH){
      *(uint4*)&Alds[nxt][wI] = aP;
      *(uint4*)&Blds[nxt][wI] = bP;
      if (kt + 2 < NCH){
        aP = *(const uint4*)(Asrc + (kt+2)*32);
        bP = *(const uint4*)(Bsrc + (kt+2)*32);
      }
    }
    frag_ab a[2], b[2];
#pragma unroll
    for (int i = 0; i < 2; i++) a[i] = *(const frag_ab*)&Alds[cur][(((mh<<1)+i) << 9) + rdoff];
#pragma unroll
    for (int j = 0; j < 2; j++) b[j] = *(const frag_ab*)&Blds[cur][(((nh<<1)+j) << 9) + rdoff];
#pragma unroll
    for (int i = 0; i < 2; i++)
#pragma unroll
      for (int j = 0; j < 2; j++)
        acc[i][j] = __builtin_amdgcn_mfma_f32_16x16x32_bf16(a[i], b[j], acc[i][j], 0, 0, 0);
    BAR_LDS();
  }

  const int mb = m0 + mh*32 + ((lane >> 4) << 2);
#pragma unroll
  for (int j = 0; j < 2; j++){
    const int kg = n0 + nh*32 + j*16 + (lane & 15);
    const float bv = bias[kg];
#pragma unroll
    for (int i = 0; i < 2; i++)
#pragma unroll
      for (int rr = 0; rr < 4; rr++)
        outF[(size_t)(mb + i*16 + rr)*256 + kg] = acc[i][j][rr] + bv;
  }
}

// ---------------------------------------------------------------------------
// RSSM scan v6.1: identical structure to v6, but __launch_bounds__(384, 1).
// v6 came out at VGPR=96/SGPR=112: the compiler could not keep whh2[64]/
// wihz[16]/wpx[64]/hsu[64] resident and rematerialized the weight loads
// inside the t-loop (L2 hits -> invisible in FETCH_SIZE, but ~64 loads/
// thread/step of ~200cy latency at 1.5 waves/SIMD). min-waves=1 lifts the
// VGPR cap to ~512 so the full working set stays in registers; the t-loop
// then touches memory only for the prefetched GIA/POF/eps streams.
// (Scan runs 32 blocks on 32 CUs = 1 block/CU; occupancy >1 wave/EU is
// useless here, so the cap costs nothing.)
// ---------------------------------------------------------------------------
__global__ void __launch_bounds__(384, 1)
rssm_scan5(const unsigned* __restrict__ g_whh2, const unsigned* __restrict__ g_wihz,
           const unsigned* __restrict__ g_pr2,  const unsigned* __restrict__ g_po2,
           const float* __restrict__ GIA, const float* __restrict__ POF,
           const float* __restrict__ eps, const float* __restrict__ bhh,
           const float* __restrict__ pr_b, float* __restrict__ out)
{
  __shared__ __align__(16) _Float16 sh_h[128];
  __shared__ __align__(16) _Float16 sh_z[32];
  __shared__ float sh_gi[384];
  __shared__ float sh_gh[384];

  const int b = blockIdx.x, tid = threadIdx.x;
  const int wv = tid >> 6, lane = tid & 63;

  unsigned whh2[64];
#pragma unroll
  for (int c = 0; c < 64; c++) whh2[c] = g_whh2[c*384 + tid];
  unsigned wihz[16];
#pragma unroll
  for (int c = 0; c < 16; c++) wihz[c] = g_wihz[c*384 + tid];
  const float bhh_i = bhh[tid];

  unsigned wpx[64];
  float prbr = 0.f;
  if (wv == 0){
#pragma unroll
    for (int c = 0; c < 64; c++) wpx[c] = g_pr2[c*64 + lane];
    prbr = pr_b[lane];
  } else if (wv == 1){
#pragma unroll
    for (int c = 0; c < 64; c++) wpx[c] = g_po2[c*64 + lane];
  } else {
#pragma unroll
    for (int c = 0; c < 64; c++) wpx[c] = 0u;
  }

  unsigned hsu[64];
#pragma unroll
  for (int c = 0; c < 64; c++) hsu[c] = 0u;

  if (tid < 128) sh_h[tid] = (_Float16)0.f;
  if (tid < 32)  sh_z[tid] = (_Float16)0.f;

  float GIAr = GIA[(size_t)(b*64)*384 + tid];
  float POFr = (wv == 1) ? POF[(size_t)(b*64)*64 + lane] : 0.f;
  float epsr = (wv == 1 && lane < 32) ? eps[(size_t)(b*64)*32 + lane] : 0.f;

  const int OFF_MUP = 0;
  const int OFF_LVP = Bn*Tn*Ln;
  const int OFF_MUQ = 2*Bn*Tn*Ln;
  const int OFF_LVQ = 3*Bn*Tn*Ln;
  const int OFF_H   = 4*Bn*Tn*Ln;
  const int OFF_Z   = 4*Bn*Tn*Ln + Bn*Tn*Hn;

  float hreg = 0.f;
  __syncthreads();

  for (int t = 0; t < Tn; t++){
    const size_t bt = (size_t)b*64 + t;

    // ---- phase A: gi (GIA + z-dot, LDS) and gh (scalar-h dot, no LDS) ----
    {
      const uint4* Z4 = (const uint4*)sh_z;
      uint4 z0 = Z4[0], z1 = Z4[1], z2 = Z4[2], z3 = Z4[3];
      float a0 = GIAr, a1 = 0.f, a2 = 0.f, a3 = 0.f;
      a0 = fdot2u(wihz[0],  z0.x, a0); a1 = fdot2u(wihz[1],  z0.y, a1);
      a2 = fdot2u(wihz[2],  z0.z, a2); a3 = fdot2u(wihz[3],  z0.w, a3);
      a0 = fdot2u(wihz[4],  z1.x, a0); a1 = fdot2u(wihz[5],  z1.y, a1);
      a2 = fdot2u(wihz[6],  z1.z, a2); a3 = fdot2u(wihz[7],  z1.w, a3);
      a0 = fdot2u(wihz[8],  z2.x, a0); a1 = fdot2u(wihz[9],  z2.y, a1);
      a2 = fdot2u(wihz[10], z2.z, a2); a3 = fdot2u(wihz[11], z2.w, a3);
      a0 = fdot2u(wihz[12], z3.x, a0); a1 = fdot2u(wihz[13], z3.y, a1);
      a2 = fdot2u(wihz[14], z3.z, a2); a3 = fdot2u(wihz[15], z3.w, a3);

      float g0 = bhh_i, g1 = 0.f, g2 = 0.f, g3 = 0.f;
#pragma unroll
      for (int c = 0; c < 64; c += 4){
        g0 = fdot2u(whh2[c],   hsu[c],   g0);
        g1 = fdot2u(whh2[c+1], hsu[c+1], g1);
        g2 = fdot2u(whh2[c+2], hsu[c+2], g2);
        g3 = fdot2u(whh2[c+3], hsu[c+3], g3);
      }
      sh_gi[tid] = (a0 + a1) + (a2 + a3);
      sh_gh[tid] = (g0 + g1) + (g2 + g3);
    }
    if (t < Tn-1) GIAr = GIA[(bt+1)*384 + tid];
    BAR_LDS();

    // ---- phase B: gates (threads 0..127) ----
    if (tid < 128){
      const float r  = sigmoid_fast(sh_gi[tid]       + sh_gh[tid]);
      const float zg = sigmoid_fast(sh_gi[128 + tid] + sh_gh[128 + tid]);
      const float nn = tanh_fast(fmaf(r, sh_gh[256 + tid], sh_gi[256 + tid]));
      hreg = (1.f - zg)*nn + zg*hreg;
      sh_h[tid] = (_Float16)hreg;
      out[OFF_H + bt*128 + tid] = hreg;
    }
    BAR_LDS();

    // ---- phase C: refill uniform h; wave0 prior; wave1 post + z ----
    {
      unsigned hv = ((const unsigned*)sh_h)[lane];
#pragma unroll
      for (int c = 0; c < 64; c++) hsu[c] = __builtin_amdgcn_readlane(hv, c);
    }
    if (wv == 0){
      float p0 = prbr, p1 = 0.f, p2 = 0.f, p3 = 0.f;
#pragma unroll
      for (int c = 0; c < 64; c += 4){
        p0 = fdot2u(wpx[c],   hsu[c],   p0);
        p1 = fdot2u(wpx[c+1], hsu[c+1], p1);
        p2 = fdot2u(wpx[c+2], hsu[c+2], p2);
        p3 = fdot2u(wpx[c+3], hsu[c+3], p3);
      }
      const float p = (p0 + p1) + (p2 + p3);
      if (lane < 32) out[OFF_MUP + bt*32 + lane] = p;
      else           out[OFF_LVP + bt*32 + (lane - 32)] = p;
    } else if (wv == 1){
      float p0 = POFr, p1 = 0.f, p2 = 0.f, p3 = 0.f;
#pragma unroll
      for (int c = 0; c < 64; c += 4){
        p0 = fdot2u(wpx[c],   hsu[c],   p0);
        p1 = fdot2u(wpx[c+1], hsu[c+1], p1);
        p2 = fdot2u(wpx[c+2], hsu[c+2], p2);
        p3 = fdot2u(wpx[c+3], hsu[c+3], p3);
      }
      const float p = (p0 + p1) + (p2 + p3);
      const float q = __shfl_xor(p, 32);
      if (lane < 32){
        out[OFF_MUQ + bt*32 + lane] = p;
        const float zz = fmaf(__expf(0.5f*q), epsr, p);
        sh_z[lane] = (_Float16)zz;
        out[OFF_Z + bt*32 + lane] = zz;
      } else {
        out[OFF_LVQ + bt*32 + (lane - 32)] = p;
      }
      if (t < Tn-1){
        POFr = POF[(bt+1)*64 + lane];
        if (lane < 32) epsr = eps[(bt+1)*32 + lane];
      }
    }
    BAR_LDS();
  }
}

// ---------------------------------------------------------------------------
extern "C" void kernel_launch(void* const* d_in, const int* in_sizes, int n_in,
                              void* d_out, int out_size, void* d_ws, size_t ws_size,
                              hipStream_t stream)
{
  const float* states = (const float*)d_in[0];
  const float* actions= (const float*)d_in[1];
  const float* c1_w = (const float*)d_in[2];  const float* c1_b = (const float*)d_in[3];
  const float* c2_w = (const float*)d_in[4];  const float* c2_b = (const float*)d_in[5];
  const float* c3_w = (const float*)d_in[6];  const float* c3_b = (const float*)d_in[7];
  const float* c4_w = (const float*)d_in[8];  const float* c4_b = (const float*)d_in[9];
  const float* fc_w = (const float*)d_in[10]; const float* fc_b = (const float*)d_in[11];
  const float* gwih = (const float*)d_in[12]; const float* gwhh = (const float*)d_in[13];
  const float* gbih = (const float*)d_in[14]; const float* gbhh = (const float*)d_in[15];
  const float* pr_w = (const float*)d_in[16]; const float* pr_b = (const float*)d_in[17];
  const float* po_w = (const float*)d_in[18]; const float* po_b = (const float*)d_in[19];
  const float* eps  = (const float*)d_in[20];

  char* p = (char*)d_ws;
  auto alloc = [&](size_t bytes){ char* r = p; p += (bytes + 255) & ~255ULL; return r; };

  unsigned short* statesB = (unsigned short*)alloc((size_t)Nimg*4096*4*2); // NHWC c=4
  unsigned short* act1    = (unsigned short*)alloc((size_t)Nimg*1024*32*2);
  unsigned short* act2    = (unsigned short*)alloc((size_t)Nimg*256*64*2);
  unsigned short* act3    = (unsigned short*)alloc((size_t)Nimg*64*128*2);
  unsigned short* act4    = (unsigned short*)alloc((size_t)Nimg*16*256*2);
  float*          feats   = (float*)alloc((size_t)Nimg*FDn*4);
  unsigned short* w1p     = (unsigned short*)alloc(32*64*2);
  unsigned short* w2p     = (unsigned short*)alloc((size_t)64*512*2);
  unsigned short* w3p     = (unsigned short*)alloc((size_t)128*1024*2);
  unsigned short* w4p     = (unsigned short*)alloc((size_t)256*2048*2);
  unsigned short* wfcp    = (unsigned short*)alloc((size_t)256*4096*2);
  unsigned* g_whh2 = (unsigned*)alloc((size_t)24576*4);
  unsigned* g_wihz = (unsigned*)alloc((size_t)6144*4);
  unsigned* g_pr2  = (unsigned*)alloc((size_t)4096*4);
  unsigned* g_po2  = (unsigned*)alloc((size_t)4096*4);
  float*    GIAb   = (float*)alloc((size_t)786432*4);
  float*    POFb   = (float*)alloc((size_t)Nimg*64*4);

  states_nhwc_kernel<<<Nimg*4096/256, 256, 0, stream>>>(states, statesB);
  prep2_kernel<<<6944, 256, 0, stream>>>(c1_w, c2_w, c3_w, c4_w, fc_w,
                                         gwhh, gwih, pr_w, po_w,
                                         w1p, w2p, w3p, w4p, wfcp,
                                         g_whh2, g_wihz, g_pr2, g_po2);
  gia_kernel<<<Nimg/8, 384, 0, stream>>>(actions, gwih, gbih, GIAb);

  // encoder: NHWC implicit-GEMM MFMA convs (BM=128, swizzled dbuf)
  convN_mfma<4,64,32,32,32,10>  <<< dim3(Nimg*1024/128, 1), 256, 0, stream >>>(statesB, w1p, c1_b, act1);
  convN_mfma<32,32,64,16,64,8>  <<< dim3(Nimg*256/128, 1), 256, 0, stream >>>(act1, w2p, c2_b, act2);
  convN_mfma<64,16,128,8,128,6> <<< dim3(Nimg*64/128, 1), 256, 0, stream >>>(act2, w3p, c3_b, act3);
  convN_mfma<128,8,256,4,128,4> <<< dim3(Nimg*16/128, 2), 256, 0, stream >>>(act3, w4p, c4_b, act4);

  fc_mfma2<<< dim3(Nimg/64, 4), 256, 0, stream >>>(act4, wfcp, fc_b, feats);
  pof_kernel<<< Nimg/8, 256, 0, stream >>>(feats, po_w, po_b, POFb);

  rssm_scan5<<< Bn, 384, 0, stream >>>(g_whh2, g_wihz, g_pr2, g_po2,
                                       GIAb, POFb, eps, gbhh, pr_b, (float*)d_out);
}